// Round 17
// baseline (258.027 us; speedup 1.0000x reference)
//
#include <hip/hip_runtime.h>
#include <stdint.h>

// NeuralMemory (Titans-style) for MI355X / gfx950.
//  prep_all (1 dispatch) -> norms_only + proj -> kv GEMM (+kT epilogue) /
//  q GEMM -> mlp_fwd (W0 in LDS, w1 frags from global; 2 blk/CU) ->
//  grad_op -> scan (folds w+U -> W) -> retrieve -> combine GEMM.
//  GEMM: 128x128 tile, 4 waves x (64x64), 2-buffer LDS (64KB, 2 blk/CU),
//  issue-early global_load_lds. [History: r11 3-buf regressed; r13 counted
//  vmcnt neutral; r14 fusion regressed; r17: double compute-per-barrier.]

#define SEQ 4096
#define NTOK 8192

typedef unsigned short u16;
typedef __attribute__((ext_vector_type(8))) short short8;
typedef __attribute__((ext_vector_type(4))) float f32x4;
typedef __attribute__((ext_vector_type(2))) unsigned int u32x2;

__device__ __forceinline__ u16 f2b(float f) {
  union { float f; uint32_t u; } c; c.f = f;
  uint32_t u = c.u;
  uint32_t r = (u + 0x7fffu + ((u >> 16) & 1u)) >> 16;
  return (u16)r;
}
__device__ __forceinline__ float b2f(u16 h) {
  union { uint32_t u; float f; } c; c.u = ((uint32_t)h) << 16;
  return c.f;
}
__device__ __forceinline__ float sigm(float x) { return 1.f / (1.f + __expf(-x)); }
__device__ __forceinline__ uint32_t pk2(float a, float b) {
  return (uint32_t)f2b(a) | ((uint32_t)f2b(b) << 16);
}
__device__ __forceinline__ void gl16(const void* g, void* l) {
  __builtin_amdgcn_global_load_lds(
      (const __attribute__((address_space(1))) unsigned int*)g,
      (__attribute__((address_space(3))) unsigned int*)l, 16, 0, 0);
}

__device__ __forceinline__ int sidx(int r, int c) {
  return r*128 + ((((c>>3) ^ (r&7))<<3) | (c&7));
}
__device__ __forceinline__ short8 frag_row_lds128(const u16* buf, int row, int ks, int l4) {
  int g = ks*4 + l4;
  return *(const short8*)&buf[row*128 + ((g ^ (row&7))<<3)];
}
__device__ __forceinline__ short8 frag_tile(const u16* t, int row, int ks, int l4) {
  return *(const short8*)&t[row*64 + (((ks*4 + l4) ^ (row&7))<<3)];
}
__device__ __forceinline__ int taddr(int c, int r0) {
  return c*64 + (r0 ^ ((c&7)<<3));
}

// ---------------- prep_all: all weight prep in one dispatch ----------------
// blocks 0..511   : transpose wkv   (1024x2048 -> wkvT)
// blocks 512..767 : transpose wq    (1024x1024 -> wqT)
// blocks 768..1023: transpose wcomb (1024x1024 -> wcombT)
// blocks 1024..1087: smallprep (w0/w1 -> w0Ts/w1Ts swizzled, w1Tp/w1bp plain)
// blocks 1088..1151: proj_prep (wstep/wgate -> Bt16)

__global__ __launch_bounds__(256) void prep_all(
    const float* __restrict__ wkv, const float* __restrict__ wq,
    const float* __restrict__ wcomb, const float* __restrict__ w0,
    const float* __restrict__ w1, const float* __restrict__ wstep,
    const float* __restrict__ wgatew,
    u16* __restrict__ wkvT, u16* __restrict__ wqT, u16* __restrict__ wcombT,
    u16* __restrict__ w0Ts, u16* __restrict__ w1Ts, u16* __restrict__ w1Tp,
    u16* __restrict__ w1bp, u16* __restrict__ Bt16)
{
  __shared__ u16 tile[64*66];
  int bid = blockIdx.x;
  int tid = threadIdx.x;
  if (bid < 1024) {
    const float* src; u16* dst; int C; int bidx;
    if (bid < 512)      { src = wkv;   dst = wkvT;   C = 2048; bidx = bid; }
    else if (bid < 768) { src = wq;    dst = wqT;    C = 1024; bidx = bid - 512; }
    else                { src = wcomb; dst = wcombT; C = 1024; bidx = bid - 768; }
    const int R = 1024;
    int tiles_x = C >> 6;
    int tx = bidx % tiles_x, ty = bidx / tiles_x;
    int c0 = tx*64, r0 = ty*64;
#pragma unroll
    for (int it=0; it<16; ++it) {
      int idx = it*256 + tid;
      int rr = idx>>6, cc = idx&63;
      tile[cc*66 + rr] = f2b(src[(size_t)(r0+rr)*C + c0+cc]);
    }
    __syncthreads();
#pragma unroll
    for (int it=0; it<16; ++it) {
      int idx = it*256 + tid;
      int rr = idx>>6, cc = idx&63;
      dst[(size_t)(c0+rr)*R + r0+cc] = tile[rr*66 + cc];
    }
  } else if (bid < 1088) {
    int id = (bid-1024)*256 + tid;     // 0..16383
    int i = id>>7, j = id&127;
    float a = w0[id], b = w1[id];
    w0Ts[sidx(j,i)] = f2b(a);
    w1Ts[sidx(j,i)] = f2b(b);
    w1Tp[j*128+i] = f2b(b);            // plain w1^T
    w1bp[id] = f2b(b);                 // plain w1
  } else {
    int id = (bid-1088)*256 + tid;     // 0..16383
    int n = id>>10, k = id&1023;
    float v = (n < 8) ? wstep[k*8 + n] : wgatew[k*8 + (n-8)];
    Bt16[id] = f2b(v);
  }
}

// ---------------- norms: streaming rmsnorm, one wave per token ----------------

__global__ __launch_bounds__(256) void norms_only(
    const float* __restrict__ seq, const float* __restrict__ gs,
    const float* __restrict__ gr, u16* __restrict__ ss, u16* __restrict__ sr)
{
  int w = threadIdx.x>>6, lane = threadIdx.x&63;
  int t = blockIdx.x*4 + w;
  const float* row = seq + (size_t)t*1024;
  f32x4 x[4];
  float ssq = 0.f;
#pragma unroll
  for (int j=0;j<4;++j) {
    x[j] = *(const f32x4*)&row[j*256 + lane*4];
    ssq += x[j][0]*x[j][0] + x[j][1]*x[j][1] + x[j][2]*x[j][2] + x[j][3]*x[j][3];
  }
  for (int m=32;m;m>>=1) ssq += __shfl_xor(ssq, m);
  float inv = rsqrtf(ssq*(1.f/1024.f) + 1e-6f);
#pragma unroll
  for (int j=0;j<4;++j) {
    int d = j*256 + lane*4;
    f32x4 g4 = *(const f32x4*)&gs[d];
    f32x4 r4 = *(const f32x4*)&gr[d];
    u32x2 ps, pr;
    ps[0] = pk2(x[j][0]*inv*g4[0], x[j][1]*inv*g4[1]);
    ps[1] = pk2(x[j][2]*inv*g4[2], x[j][3]*inv*g4[3]);
    pr[0] = pk2(x[j][0]*inv*r4[0], x[j][1]*inv*r4[1]);
    pr[1] = pk2(x[j][2]*inv*r4[2], x[j][3]*inv*r4[3]);
    *(u32x2*)&ss[(size_t)t*1024 + d] = ps;
    *(u32x2*)&sr[(size_t)t*1024 + d] = pr;
  }
}

// ---------------- proj: lr/gate via MFMA skinny GEMM ----------------

__global__ __launch_bounds__(64) void proj_kernel(
    const u16* __restrict__ ss, const u16* __restrict__ sr,
    const u16* __restrict__ Bt16, float* __restrict__ lr,
    float* __restrict__ gate)
{
  int lane = threadIdx.x;
  int l15 = lane&15, l4 = lane>>4;
  size_t t0 = (size_t)blockIdx.x*16;
  f32x4 acc1 = {}, acc2 = {};
#pragma unroll 8
  for (int ks=0; ks<32; ++ks) {
    int kof = ks*32 + l4*8;
    short8 bf = *(const short8*)&Bt16[l15*1024 + kof];
    short8 as = *(const short8*)&ss[(t0+l15)*1024 + kof];
    short8 ar = *(const short8*)&sr[(t0+l15)*1024 + kof];
    acc1 = __builtin_amdgcn_mfma_f32_16x16x32_bf16(as, bf, acc1, 0,0,0);
    acc2 = __builtin_amdgcn_mfma_f32_16x16x32_bf16(ar, bf, acc2, 0,0,0);
  }
  int col = l15;
#pragma unroll
  for (int j=0;j<4;++j) {
    int t = (int)t0 + l4*4 + j;
    int b = t>>12, pos = t&4095;
    if (col < 8) lr[((size_t)(b*8+col))*4096 + pos] = sigm(acc1[j])*0.01f;
    else gate[((size_t)(b*8+(col-8)))*4096 + pos] = sigm(acc2[j]);
  }
}

// ---------------- per-chunk gates from cmean (vectorized loads) ----------------

__global__ __launch_bounds__(256) void chunkgates_kernel(
    const u16* __restrict__ ss, const float* __restrict__ wmom,
    const float* __restrict__ wdec, float* __restrict__ mg,
    float* __restrict__ d1m)
{
  int bc = blockIdx.x; int b = bc>>6, ch = bc&63;
  size_t t0 = (size_t)(b*4096 + ch*64)*1024;
  int tid = threadIdx.x;
  int d0 = tid*4;
  float cm[4]; cm[0]=cm[1]=cm[2]=cm[3]=0.f;
  for (int tok=0; tok<64; ++tok) {
    u32x2 v2 = *(const u32x2*)&ss[t0 + (size_t)tok*1024 + d0];
    cm[0] += b2f((u16)(v2[0] & 0xffffu));
    cm[1] += b2f((u16)(v2[0] >> 16));
    cm[2] += b2f((u16)(v2[1] & 0xffffu));
    cm[3] += b2f((u16)(v2[1] >> 16));
  }
  float pm[8], pd[8];
#pragma unroll
  for (int h=0;h<8;++h){ pm[h]=0.f; pd[h]=0.f; }
#pragma unroll
  for (int i=0;i<4;++i) {
    float v = cm[i]*(1.f/64.f);
    int d = d0 + i;
#pragma unroll
    for (int h=0;h<8;++h){ pm[h]+=v*wmom[d*8+h]; pd[h]+=v*wdec[d*8+h]; }
  }
#pragma unroll
  for (int h=0;h<8;++h)
    for (int m=32;m;m>>=1){ pm[h] += __shfl_xor(pm[h],m); pd[h] += __shfl_xor(pd[h],m); }
  __shared__ float r2[4][16];
  int wv = tid>>6;
  if ((tid&63)==0) {
#pragma unroll
    for (int h=0;h<8;++h){ r2[wv][h]=pm[h]; r2[wv][8+h]=pd[h]; }
  }
  __syncthreads();
  if (tid < 16) {
    float s = r2[0][tid]+r2[1][tid]+r2[2][tid]+r2[3][tid];
    if (tid<8) mg[(b*8+tid)*64 + ch] = sigm(s);
    else d1m[(b*8+(tid-8))*64 + ch] = 1.f - sigm(s);
  }
}

// ---------------- generic bf16 GEMM: C = A(MxK) @ Bt(NxK)^T ----------------
// 256 threads, 4 waves (2M x 2N), wave tile 64x64 (acc 4x4): 2x compute per
// barrier vs the 8-wave form at the same 64KB LDS / 2 blocks/CU.
// 2-buffer, issue-early staging: STAGE(next) -> ds_read+MFMA(cur) ->
// vmcnt(0)+barrier. kvT != nullptr (kv GEMM only): keys half (col<1024) also
// stored as per-chunk transposed tiles kT[chunk][d:128][r:64] (XOR-swizzled).

__global__ __launch_bounds__(256, 2) void gemm_bt(
    const u16* __restrict__ A, const u16* __restrict__ Bt,
    void* __restrict__ C, int M, int N, int K, int out_f32,
    u16* __restrict__ kvT)
{
  __shared__ __align__(16) u16 As[2][128*64];
  __shared__ __align__(16) u16 Bs[2][128*64];
  int tid = threadIdx.x;
  int w = tid>>6, lane = tid&63;      // w in 0..3
  int wr = w>>1, wc = w&1;            // 2x2 wave grid, tile 64x64
  int l15 = lane&15, l4 = lane>>4;
  int rl = lane>>3;
  int cg = (lane&7) ^ rl;
  int nwg = gridDim.x*gridDim.y;
  int wg  = blockIdx.y*gridDim.x + blockIdx.x;
  int cpx = nwg >> 3;
  int swz = (wg & 7)*cpx + (wg >> 3);
  int bx = swz % gridDim.x, by = swz / gridDim.x;
  int brow = by*128, bcol = bx*128;
  f32x4 acc[4][4] = {};

  auto STAGE = [&](int buf, int kt) {
#pragma unroll
    for (int i=0;i<4;++i) {
      int row = w*32 + i*8;
      gl16(&A [(size_t)(brow+row+rl)*K + kt + cg*8], &As[buf][row*64]);
      gl16(&Bt[(size_t)(bcol+row+rl)*K + kt + cg*8], &Bs[buf][row*64]);
    }
  };

  int nk = K >> 6;
  STAGE(0, 0);
  asm volatile("s_waitcnt vmcnt(0)");
  __syncthreads();
  for (int t=0; t<nk; ++t) {
    int cur = t & 1;
    if (t+1 < nk) STAGE(cur^1, (t+1)*64);
#pragma unroll
    for (int ks=0; ks<2; ++ks) {
      short8 af[4], bf[4];
#pragma unroll
      for (int m=0;m<4;++m) {
        int row = wr*64 + m*16 + l15;
        int g = ks*4 + l4;
        af[m] = *(const short8*)&As[cur][row*64 + ((g ^ (row&7))<<3)];
      }
#pragma unroll
      for (int n=0;n<4;++n) {
        int row = wc*64 + n*16 + l15;
        int g = ks*4 + l4;
        bf[n] = *(const short8*)&Bs[cur][row*64 + ((g ^ (row&7))<<3)];
      }
#pragma unroll
      for (int m=0;m<4;++m)
#pragma unroll
        for (int n=0;n<4;++n)
          acc[m][n] = __builtin_amdgcn_mfma_f32_16x16x32_bf16(af[m], bf[n], acc[m][n], 0,0,0);
    }
    asm volatile("s_waitcnt vmcnt(0)");
    __syncthreads();
  }
#pragma unroll
  for (int m=0;m<4;++m) {
#pragma unroll
    for (int n=0;n<4;++n) {
      int col = bcol + wc*64 + n*16 + l15;
#pragma unroll
      for (int j=0;j<4;++j) {
        int row = brow + wr*64 + m*16 + l4*4 + j;
        if (out_f32) ((float*)C)[(size_t)row*N + col] = acc[m][n][j];
        else ((u16*)C)[(size_t)row*N + col] = f2b(acc[m][n][j]);
      }
    }
  }
  if (kvT) {
#pragma unroll
    for (int m=0;m<4;++m) {
#pragma unroll
      for (int n=0;n<4;++n) {
        int col = bcol + wc*64 + n*16 + l15;
        if (col < 1024) {
          int row0 = brow + wr*64 + m*16 + l4*4;
          int d = col & 127;
          int chunk = ((row0>>12)*8 + (col>>7))*64 + ((row0&4095)>>6);
          int rr = row0 & 63;
          u32x2 p; p[0] = pk2(acc[m][n][0], acc[m][n][1]);
                   p[1] = pk2(acc[m][n][2], acc[m][n][3]);
          *(u32x2*)&kvT[(size_t)chunk*8192 + taddr(d, rr)] = p;
        }
      }
    }
  }
}

// ---------------- mlp_fwd: W0 in LDS; w1 frags from global (2 blk/CU) ----------------

__global__ __launch_bounds__(512) void mlp_fwd(
    const u16* __restrict__ kvout, const float* __restrict__ lr,
    const u16* __restrict__ w0Ts, const u16* __restrict__ w1Tp,
    const u16* __restrict__ w1bp,
    u16* __restrict__ aTg, u16* __restrict__ dpTg, u16* __restrict__ dxTg)
{
  __shared__ __align__(16) u16 W0L[16384];
  __shared__ __align__(16) u16 abuf[16384];
  int tid = threadIdx.x;
  int w = tid>>6, lane = tid&63;
  int l15 = lane&15, l4 = lane>>4;
#pragma unroll
  for (int it=0; it<4; ++it) {
    int wb = it*512 + w*64;
    gl16((const short8*)w0Ts + wb + lane, (short8*)W0L + wb);
  }
  __syncthreads();
  u16* ab = abuf + w*2048;
  int r0 = l4*4;
  int q = w&3, half = w>>2;
  int rb = q*16;
  int cidx = blockIdx.x*2 + half;
  int bh = cidx>>6, ch = cidx&63;
  int b = bh>>3, hh = bh&7;
  size_t t0 = (size_t)(b*4096 + ch*64 + rb);
  size_t tout = (size_t)cidx*8192;
  f32x4 lrv = *(const f32x4*)&lr[(size_t)bh*4096 + ch*64 + rb + r0];

  // x1 = k @ w0 (A-frags direct global; B from LDS)
  f32x4 x1[8] = {};
#pragma unroll
  for (int ks=0; ks<4; ++ks) {
    short8 af = *(const short8*)&kvout[(t0 + l15)*2048 + hh*128 + ks*32 + l4*8];
#pragma unroll
    for (int n=0;n<8;++n) {
      short8 bf = frag_row_lds128(W0L, n*16+l15, ks, l4);
      x1[n] = __builtin_amdgcn_mfma_f32_16x16x32_bf16(af, bf, x1[n], 0,0,0);
    }
  }
#pragma unroll
  for (int n=0;n<8;++n) {
    int c = n*16 + l15;
    float av[4];
#pragma unroll
    for (int j=0;j<4;++j){ float xv = x1[n][j]; av[j] = xv*sigm(xv); }
    ab[sidx(r0+0,c)] = f2b(av[0]);
    ab[sidx(r0+1,c)] = f2b(av[1]);
    ab[sidx(r0+2,c)] = f2b(av[2]);
    ab[sidx(r0+3,c)] = f2b(av[3]);
    u32x2 p; p[0] = pk2(av[0],av[1]); p[1] = pk2(av[2],av[3]);
    *(u32x2*)&aTg[tout + taddr(c, rb + r0)] = p;
  }
  // pred = a @ w1 (B-frags from plain global w1^T; L2-resident 32KB)
  f32x4 pr[8] = {};
#pragma unroll
  for (int ks=0; ks<4; ++ks) {
    short8 af = frag_row_lds128(ab, l15, ks, l4);
    int kof = ks*32 + l4*8;
#pragma unroll
    for (int n=0;n<8;++n) {
      short8 bf = *(const short8*)&w1Tp[(size_t)(n*16+l15)*128 + kof];
      pr[n] = __builtin_amdgcn_mfma_f32_16x16x32_bf16(af, bf, pr[n], 0,0,0);
    }
  }
#pragma unroll
  for (int n=0;n<8;++n) {
    int c = n*16 + l15;
    float dv[4];
#pragma unroll
    for (int j=0;j<4;++j) {
      float vv = b2f(kvout[(t0+r0+j)*2048 + 1024 + hh*128 + c]);
      dv[j] = 0.015625f * lrv[j] * (pr[n][j] - vv);
    }
    ab[sidx(r0+0,c)] = f2b(dv[0]);
    ab[sidx(r0+1,c)] = f2b(dv[1]);
    ab[sidx(r0+2,c)] = f2b(dv[2]);
    ab[sidx(r0+3,c)] = f2b(dv[3]);
    u32x2 p; p[0] = pk2(dv[0],dv[1]); p[1] = pk2(dv[2],dv[3]);
    *(u32x2*)&dpTg[tout + taddr(c, rb + r0)] = p;
  }
  // da = dpred @ w1^T (B-frags from plain global w1)
  f32x4 da[8] = {};
#pragma unroll
  for (int ks=0; ks<4; ++ks) {
    short8 af = frag_row_lds128(ab, l15, ks, l4);
    int kof = ks*32 + l4*8;
#pragma unroll
    for (int n=0;n<8;++n) {
      short8 bf = *(const short8*)&w1bp[(size_t)(n*16+l15)*128 + kof];
      da[n] = __builtin_amdgcn_mfma_f32_16x16x32_bf16(af, bf, da[n], 0,0,0);
    }
  }
#pragma unroll
  for (int n=0;n<8;++n) {
    int c = n*16 + l15;
    float d[4];
#pragma unroll
    for (int j=0;j<4;++j) {
      float xv = x1[n][j];
      float sg = sigm(xv);
      d[j] = da[n][j]*(sg*(1.f + xv*(1.f - sg)));
    }
    u32x2 p; p[0] = pk2(d[0],d[1]); p[1] = pk2(d[2],d[3]);
    *(u32x2*)&dxTg[tout + taddr(c, rb + r0)] = p;
  }
}

// ---------------- grad_op ----------------

__global__ __launch_bounds__(256) void grad_op(
    const u16* __restrict__ dpT, const u16* __restrict__ aT,
    const u16* __restrict__ dxT, const u16* __restrict__ kT,
    u16* __restrict__ S)
{
  __shared__ __align__(16) u16 lds[16384];
  int bid = blockIdx.x;
  int op = bid >> 10;
  int sub = bid & 1023, bh = sub>>6, ch = sub&63;
  size_t tin = (size_t)sub*8192;
  const u16* Ain = op ? (dxT + tin) : (dpT + tin);
  const u16* Bin = op ? (kT  + tin) : (aT  + tin);
  int tid = threadIdx.x;
  int w = tid>>6, lane = tid&63;
  int l15 = lane&15, l4 = lane>>4;

#pragma unroll
  for (int it=0; it<4; ++it) {
    int wb = it*256 + w*64;
    gl16((const short8*)Ain + wb + lane, (short8*)lds + wb);
    gl16((const short8*)Bin + wb + lane, (short8*)(lds+8192) + wb);
  }
  __syncthreads();

  f32x4 g[2][8] = {};
#pragma unroll
  for (int ks=0; ks<2; ++ks) {
    short8 af[2];
#pragma unroll
    for (int mi=0; mi<2; ++mi)
      af[mi] = frag_tile(lds, w*32 + mi*16 + l15, ks, l4);
#pragma unroll
    for (int n=0;n<8;++n) {
      short8 bf = frag_tile(lds+8192, n*16 + l15, ks, l4);
#pragma unroll
      for (int mi=0;mi<2;++mi)
        g[mi][n] = __builtin_amdgcn_mfma_f32_16x16x32_bf16(af[mi], bf, g[mi][n], 0,0,0);
    }
  }
  __syncthreads();

#pragma unroll
  for (int mi=0;mi<2;++mi)
#pragma unroll
    for (int n=0;n<8;++n)
#pragma unroll
      for (int j=0;j<4;++j) {
        int m = w*32 + mi*16 + l4*4 + j, c = n*16 + l15;
        lds[sidx(m,c)] = f2b(-g[mi][n][j]);
      }
  __syncthreads();

  u16* Sout = S + ((size_t)((op ? bh : 16+bh))*64 + ch)*16384;
#pragma unroll
  for (int it=0; it<8; ++it)
    ((short8*)Sout)[it*256+tid] = ((const short8*)lds)[it*256+tid];
}

// ---- scan: double linear recurrence, 2 elements/thread (u32 packed) ----

__global__ __launch_bounds__(256) void scan_kernel(
    u16* __restrict__ S, const float* __restrict__ mg, const float* __restrict__ d1m,
    const u16* __restrict__ w0Ts, const u16* __restrict__ w1Ts)
{
  int bidx = blockIdx.x;              // mbh*32 + eblk
  int eblk = bidx & 31;
  int mbh = bidx >> 5;
  int bh = mbh & 15;
  int e = (eblk*256 + threadIdx.x)*2;
  uint32_t* base = (uint32_t*)(S + (size_t)mbh*64*16384 + e);
  const u16* wsrc = (mbh < 16) ? w0Ts : w1Ts;
  uint32_t wp = *(const uint32_t*)&wsrc[e];
  float wv0 = b2f((u16)(wp & 0xffffu)), wv1 = b2f((u16)(wp >> 16));
  const float* g1 = mg + bh*64;
  const float* g2 = d1m + bh*64;
  float mom0=0.f, upd0=0.f, mom1=0.f, upd1=0.f;
  for (int c2=0; c2<64; ++c2) {
    uint32_t s2 = base[(size_t)c2*8192];
    float s0 = b2f((u16)(s2 & 0xffffu)), s1 = b2f((u16)(s2 >> 16));
    float gg1 = g1[c2], gg2 = g2[c2];
    mom0 = gg1*mom0 + s0; upd0 = gg2*upd0 + mom0;
    mom1 = gg1*mom1 + s1; upd1 = gg2*upd1 + mom1;
    base[(size_t)c2*8192] = pk2(wv0 + upd0, wv1 + upd1);
  }
}

// ---------------- retrieval (ch==0 blocks also zero the pad rows) ----------------

__global__ __launch_bounds__(256) void retrieve_kernel(
    const u16* __restrict__ qn, const u16* __restrict__ W,
    const float* __restrict__ gamma, const float* __restrict__ gate,
    u16* __restrict__ vals)
{
  __shared__ __align__(16) u16 W0s[16384];
  __shared__ __align__(16) u16 W1s[16384];
  __shared__ __align__(16) u16 QA[8192];
  int bid = blockIdx.x;
  int bh = bid>>6, ch = bid&63;
  int b = bh>>3, h = bh&7;
  int tid = threadIdx.x;
  int w = tid>>6, lane = tid&63;
  int l15 = lane&15, l4 = lane>>4;
  const u16* W0g = W + ((size_t)bh*64 + ch)*16384;
  const u16* W1g = W + ((size_t)(16+bh)*64 + ch)*16384;
#pragma unroll
  for (int it=0; it<8; ++it) {
    int wb = it*256 + w*64;
    gl16((const short8*)W0g + wb + lane, (short8*)W0s + wb);
    gl16((const short8*)W1g + wb + lane, (short8*)W1s + wb);
  }
  if (ch == 0) {
    for (int r = w; r < 63; r += 4)
      *(uint32_t*)&vals[((size_t)(b*4096 + r))*1024 + h*128 + lane*2] = 0;
  }
  u16* qa = QA + w*2048;
#pragma unroll
  for (int it=0; it<4; ++it) {
    int task = it*64 + lane;
    int rloc = task>>4, g = task&15;
    int posn = ch*64 + w*16 + rloc + 63;
    short8 v;
    if (posn < 4096) v = *(const short8*)&qn[((size_t)(b*4096+posn))*1024 + h*128 + g*8];
    else {
#pragma unroll
      for (int i=0;i<8;++i) v[i]=0;
    }
    *(short8*)&qa[rloc*128 + ((g ^ (rloc&7))<<3)] = v;
  }
  __syncthreads();
  f32x4 xx[8] = {};
#pragma unroll
  for (int ks=0; ks<4; ++ks) {
    short8 af = frag_row_lds128(qa, l15, ks, l4);
#pragma unroll
    for (int n=0;n<8;++n) {
      short8 bf = frag_row_lds128(W0s, n*16+l15, ks, l4);
      xx[n] = __builtin_amdgcn_mfma_f32_16x16x32_bf16(af, bf, xx[n], 0,0,0);
    }
  }
  int r0 = l4*4;
#pragma unroll
  for (int n=0;n<8;++n) {
    int c = n*16 + l15;
#pragma unroll
    for (int j=0;j<4;++j) {
      float xv = xx[n][j];
      qa[sidx(r0+j,c)] = f2b(xv * sigm(xv));
    }
  }
  f32x4 vv[8] = {};
#pragma unroll
  for (int ks=0; ks<4; ++ks) {
    short8 af = frag_row_lds128(qa, l15, ks, l4);
#pragma unroll
    for (int n=0;n<8;++n) {
      short8 bf = frag_row_lds128(W1s, n*16+l15, ks, l4);
      vv[n] = __builtin_amdgcn_mfma_f32_16x16x32_bf16(af, bf, vv[n], 0,0,0);
    }
  }
#pragma unroll
  for (int j=0;j<4;++j) {
    float ssq = 0.f;
#pragma unroll
    for (int n=0;n<8;++n) ssq += vv[n][j]*vv[n][j];
    ssq += __shfl_xor(ssq,1); ssq += __shfl_xor(ssq,2);
    ssq += __shfl_xor(ssq,4); ssq += __shfl_xor(ssq,8);
    float rms = rsqrtf(ssq*(1.f/128.f) + 1e-6f);
    int posn = ch*64 + w*16 + r0 + j + 63;
    if (posn < 4096) {
      float gt = gate[(size_t)bh*4096 + posn];
      size_t orow = ((size_t)(b*4096+posn))*1024 + h*128;
#pragma unroll
      for (int n=0;n<8;++n) {
        int c = n*16 + l15;
        vals[orow + c] = f2b(vv[n][j]*rms*(1.f + gamma[h*128+c])*gt);
      }
    }
  }
}

extern "C" void kernel_launch(void* const* d_in, const int* in_sizes, int n_in,
                              void* d_out, int out_size, void* d_ws, size_t ws_size,
                              hipStream_t stream) {
  const float* seq    = (const float*)d_in[0];
  const float* gstore = (const float*)d_in[1];
  const float* gret   = (const float*)d_in[2];
  const float* wkv    = (const float*)d_in[3];
  const float* wq     = (const float*)d_in[4];
  const float* wstep  = (const float*)d_in[5];
  const float* wmom   = (const float*)d_in[6];
  const float* wdec   = (const float*)d_in[7];
  const float* wgatew = (const float*)d_in[8];
  const float* wcomb  = (const float*)d_in[9];
  const float* gamma  = (const float*)d_in[10];
  const float* w0f    = (const float*)d_in[11];
  const float* w1f    = (const float*)d_in[12];
  float* out = (float*)d_out;
  (void)in_sizes; (void)n_in; (void)out_size; (void)ws_size;

  char* p = (char*)d_ws;
  size_t off = 0;
  auto alloc = [&](size_t bytes) -> void* {
    void* r = p + off; off += (bytes + 255) & ~(size_t)255; return r;
  };
  u16* wkvT   = (u16*)alloc((size_t)2048*1024*2);
  u16* wqT    = (u16*)alloc((size_t)1024*1024*2);
  u16* wcombT = (u16*)alloc((size_t)1024*1024*2);
  u16* w0Ts   = (u16*)alloc(16384*2);
  u16* w1Ts   = (u16*)alloc(16384*2);
  u16* w1Tp   = (u16*)alloc(16384*2);
  u16* w1bp   = (u16*)alloc(16384*2);
  u16* Bt16   = (u16*)alloc(16384*2);
  u16* ss     = (u16*)alloc((size_t)NTOK*1024*2);
  u16* sr     = (u16*)alloc((size_t)NTOK*1024*2);
  u16* kvout  = (u16*)alloc((size_t)NTOK*2048*2);
  u16* qn     = (u16*)alloc((size_t)NTOK*1024*2);
  u16* vals   = (u16*)alloc((size_t)NTOK*1024*2);
  float* lr   = (float*)alloc((size_t)16*4096*4);
  float* gate = (float*)alloc((size_t)16*4096*4);
  float* mg   = (float*)alloc(1024*4);
  float* d1m  = (float*)alloc(1024*4);
  u16* S      = (u16*)alloc((size_t)32*64*16384*2);
  u16* kTg    = (u16*)alloc((size_t)1024*8192*2);
  u16* aTg    = (u16*)alloc((size_t)1024*8192*2);
  u16* dpTg   = (u16*)alloc((size_t)1024*8192*2);
  u16* dxTg   = (u16*)alloc((size_t)1024*8192*2);

  prep_all<<<dim3(1152),dim3(256),0,stream>>>(wkv, wq, wcomb, w0f, w1f, wstep, wgatew,
                                              wkvT, wqT, wcombT, w0Ts, w1Ts, w1Tp, w1bp, Bt16);
  norms_only<<<dim3(2048),dim3(256),0,stream>>>(seq, gstore, gret, ss, sr);
  proj_kernel<<<dim3(512),dim3(64),0,stream>>>(ss, sr, Bt16, lr, gate);
  chunkgates_kernel<<<dim3(128),dim3(256),0,stream>>>(ss, wmom, wdec, mg, d1m);
  gemm_bt<<<dim3(16,64),dim3(256),0,stream>>>(ss, wkvT, kvout, 8192, 2048, 1024, 0, kTg);
  gemm_bt<<<dim3(8,64),dim3(256),0,stream>>>(sr, wqT, qn, 8192, 1024, 1024, 0, nullptr);
  mlp_fwd<<<dim3(512),dim3(512),0,stream>>>(kvout, lr, w0Ts, w1Tp, w1bp, aTg, dpTg, dxTg);
  grad_op<<<dim3(2048),dim3(256),0,stream>>>(dpTg, aTg, dxTg, kTg, S);
  scan_kernel<<<dim3(1024),dim3(256),0,stream>>>(S, mg, d1m, w0Ts, w1Ts);
  retrieve_kernel<<<dim3(1024),dim3(256),0,stream>>>(qn, S, gamma, gate, vals);
  gemm_bt<<<dim3(8,64),dim3(256),0,stream>>>(vals, wcombT, out, 8192, 1024, 1024, 1, nullptr);
}

// Round 18
// 226.464 us; speedup vs baseline: 1.1394x; 1.1394x over previous
//
#include <hip/hip_runtime.h>
#include <stdint.h>

// NeuralMemory (Titans-style) for MI355X / gfx950.  r16 measured-best (226.8us).
//  prep_all (1 dispatch) -> norms_only + proj -> kv GEMM (+kT epilogue) /
//  q GEMM -> mlp_fwd (weights in LDS) -> grad_op -> scan (folds w+U -> W) ->
//  retrieve (ch==0 zeroes pad rows) -> combine GEMM.
//  GEMM: 128x128 tile, 8 waves x (64x32), 2-buffer LDS (64KB, 2 blk/CU),
//  issue-early global_load_lds.
//  [Failed experiments: r11 3-buf (1 blk/CU, FETCH x2); r13 counted-vmcnt
//   (neutral); r14 mlp+grad fusion (2B scatter stores); r17 4-wave 64x64 gemm
//   + w1-from-global mlp (both regressed). This structure is the optimum found.]

#define SEQ 4096
#define NTOK 8192

typedef unsigned short u16;
typedef __attribute__((ext_vector_type(8))) short short8;
typedef __attribute__((ext_vector_type(4))) float f32x4;
typedef __attribute__((ext_vector_type(2))) unsigned int u32x2;

__device__ __forceinline__ u16 f2b(float f) {
  union { float f; uint32_t u; } c; c.f = f;
  uint32_t u = c.u;
  uint32_t r = (u + 0x7fffu + ((u >> 16) & 1u)) >> 16;
  return (u16)r;
}
__device__ __forceinline__ float b2f(u16 h) {
  union { uint32_t u; float f; } c; c.u = ((uint32_t)h) << 16;
  return c.f;
}
__device__ __forceinline__ float sigm(float x) { return 1.f / (1.f + __expf(-x)); }
__device__ __forceinline__ uint32_t pk2(float a, float b) {
  return (uint32_t)f2b(a) | ((uint32_t)f2b(b) << 16);
}
__device__ __forceinline__ void gl16(const void* g, void* l) {
  __builtin_amdgcn_global_load_lds(
      (const __attribute__((address_space(1))) unsigned int*)g,
      (__attribute__((address_space(3))) unsigned int*)l, 16, 0, 0);
}

__device__ __forceinline__ int sidx(int r, int c) {
  return r*128 + ((((c>>3) ^ (r&7))<<3) | (c&7));
}
__device__ __forceinline__ short8 frag_row_lds128(const u16* buf, int row, int ks, int l4) {
  int g = ks*4 + l4;
  return *(const short8*)&buf[row*128 + ((g ^ (row&7))<<3)];
}
__device__ __forceinline__ short8 frag_tile(const u16* t, int row, int ks, int l4) {
  return *(const short8*)&t[row*64 + (((ks*4 + l4) ^ (row&7))<<3)];
}
__device__ __forceinline__ int taddr(int c, int r0) {
  return c*64 + (r0 ^ ((c&7)<<3));
}

// ---------------- prep_all: all weight prep in one dispatch ----------------
// blocks 0..511   : transpose wkv   (1024x2048 -> wkvT)
// blocks 512..767 : transpose wq    (1024x1024 -> wqT)
// blocks 768..1023: transpose wcomb (1024x1024 -> wcombT)
// blocks 1024..1087: smallprep (w0/w1 -> w0Ts/w1Ts/w1bs, swizzled)
// blocks 1088..1151: proj_prep (wstep/wgate -> Bt16)

__global__ __launch_bounds__(256) void prep_all(
    const float* __restrict__ wkv, const float* __restrict__ wq,
    const float* __restrict__ wcomb, const float* __restrict__ w0,
    const float* __restrict__ w1, const float* __restrict__ wstep,
    const float* __restrict__ wgatew,
    u16* __restrict__ wkvT, u16* __restrict__ wqT, u16* __restrict__ wcombT,
    u16* __restrict__ w0Ts, u16* __restrict__ w1Ts, u16* __restrict__ w1bs,
    u16* __restrict__ Bt16)
{
  __shared__ u16 tile[64*66];
  int bid = blockIdx.x;
  int tid = threadIdx.x;
  if (bid < 1024) {
    const float* src; u16* dst; int C; int bidx;
    if (bid < 512)      { src = wkv;   dst = wkvT;   C = 2048; bidx = bid; }
    else if (bid < 768) { src = wq;    dst = wqT;    C = 1024; bidx = bid - 512; }
    else                { src = wcomb; dst = wcombT; C = 1024; bidx = bid - 768; }
    const int R = 1024;
    int tiles_x = C >> 6;
    int tx = bidx % tiles_x, ty = bidx / tiles_x;
    int c0 = tx*64, r0 = ty*64;
#pragma unroll
    for (int it=0; it<16; ++it) {
      int idx = it*256 + tid;
      int rr = idx>>6, cc = idx&63;
      tile[cc*66 + rr] = f2b(src[(size_t)(r0+rr)*C + c0+cc]);
    }
    __syncthreads();
#pragma unroll
    for (int it=0; it<16; ++it) {
      int idx = it*256 + tid;
      int rr = idx>>6, cc = idx&63;
      dst[(size_t)(c0+rr)*R + r0+cc] = tile[rr*66 + cc];
    }
  } else if (bid < 1088) {
    int id = (bid-1024)*256 + tid;     // 0..16383
    int i = id>>7, j = id&127;
    float a = w0[id], b = w1[id];
    w0Ts[sidx(j,i)] = f2b(a);
    w1Ts[sidx(j,i)] = f2b(b);
    w1bs[sidx(i,j)] = f2b(b);
  } else {
    int id = (bid-1088)*256 + tid;     // 0..16383
    int n = id>>10, k = id&1023;
    float v = (n < 8) ? wstep[k*8 + n] : wgatew[k*8 + (n-8)];
    Bt16[id] = f2b(v);
  }
}

// ---------------- norms: streaming rmsnorm, one wave per token ----------------

__global__ __launch_bounds__(256) void norms_only(
    const float* __restrict__ seq, const float* __restrict__ gs,
    const float* __restrict__ gr, u16* __restrict__ ss, u16* __restrict__ sr)
{
  int w = threadIdx.x>>6, lane = threadIdx.x&63;
  int t = blockIdx.x*4 + w;
  const float* row = seq + (size_t)t*1024;
  f32x4 x[4];
  float ssq = 0.f;
#pragma unroll
  for (int j=0;j<4;++j) {
    x[j] = *(const f32x4*)&row[j*256 + lane*4];
    ssq += x[j][0]*x[j][0] + x[j][1]*x[j][1] + x[j][2]*x[j][2] + x[j][3]*x[j][3];
  }
  for (int m=32;m;m>>=1) ssq += __shfl_xor(ssq, m);
  float inv = rsqrtf(ssq*(1.f/1024.f) + 1e-6f);
#pragma unroll
  for (int j=0;j<4;++j) {
    int d = j*256 + lane*4;
    f32x4 g4 = *(const f32x4*)&gs[d];
    f32x4 r4 = *(const f32x4*)&gr[d];
    u32x2 ps, pr;
    ps[0] = pk2(x[j][0]*inv*g4[0], x[j][1]*inv*g4[1]);
    ps[1] = pk2(x[j][2]*inv*g4[2], x[j][3]*inv*g4[3]);
    pr[0] = pk2(x[j][0]*inv*r4[0], x[j][1]*inv*r4[1]);
    pr[1] = pk2(x[j][2]*inv*r4[2], x[j][3]*inv*r4[3]);
    *(u32x2*)&ss[(size_t)t*1024 + d] = ps;
    *(u32x2*)&sr[(size_t)t*1024 + d] = pr;
  }
}

// ---------------- proj: lr/gate via MFMA skinny GEMM ----------------

__global__ __launch_bounds__(64) void proj_kernel(
    const u16* __restrict__ ss, const u16* __restrict__ sr,
    const u16* __restrict__ Bt16, float* __restrict__ lr,
    float* __restrict__ gate)
{
  int lane = threadIdx.x;
  int l15 = lane&15, l4 = lane>>4;
  size_t t0 = (size_t)blockIdx.x*16;
  f32x4 acc1 = {}, acc2 = {};
#pragma unroll 8
  for (int ks=0; ks<32; ++ks) {
    int kof = ks*32 + l4*8;
    short8 bf = *(const short8*)&Bt16[l15*1024 + kof];
    short8 as = *(const short8*)&ss[(t0+l15)*1024 + kof];
    short8 ar = *(const short8*)&sr[(t0+l15)*1024 + kof];
    acc1 = __builtin_amdgcn_mfma_f32_16x16x32_bf16(as, bf, acc1, 0,0,0);
    acc2 = __builtin_amdgcn_mfma_f32_16x16x32_bf16(ar, bf, acc2, 0,0,0);
  }
  int col = l15;
#pragma unroll
  for (int j=0;j<4;++j) {
    int t = (int)t0 + l4*4 + j;
    int b = t>>12, pos = t&4095;
    if (col < 8) lr[((size_t)(b*8+col))*4096 + pos] = sigm(acc1[j])*0.01f;
    else gate[((size_t)(b*8+(col-8)))*4096 + pos] = sigm(acc2[j]);
  }
}

// ---------------- per-chunk gates from cmean (vectorized loads) ----------------

__global__ __launch_bounds__(256) void chunkgates_kernel(
    const u16* __restrict__ ss, const float* __restrict__ wmom,
    const float* __restrict__ wdec, float* __restrict__ mg,
    float* __restrict__ d1m)
{
  int bc = blockIdx.x; int b = bc>>6, ch = bc&63;
  size_t t0 = (size_t)(b*4096 + ch*64)*1024;
  int tid = threadIdx.x;
  int d0 = tid*4;
  float cm[4]; cm[0]=cm[1]=cm[2]=cm[3]=0.f;
  for (int tok=0; tok<64; ++tok) {
    u32x2 v2 = *(const u32x2*)&ss[t0 + (size_t)tok*1024 + d0];
    cm[0] += b2f((u16)(v2[0] & 0xffffu));
    cm[1] += b2f((u16)(v2[0] >> 16));
    cm[2] += b2f((u16)(v2[1] & 0xffffu));
    cm[3] += b2f((u16)(v2[1] >> 16));
  }
  float pm[8], pd[8];
#pragma unroll
  for (int h=0;h<8;++h){ pm[h]=0.f; pd[h]=0.f; }
#pragma unroll
  for (int i=0;i<4;++i) {
    float v = cm[i]*(1.f/64.f);
    int d = d0 + i;
#pragma unroll
    for (int h=0;h<8;++h){ pm[h]+=v*wmom[d*8+h]; pd[h]+=v*wdec[d*8+h]; }
  }
#pragma unroll
  for (int h=0;h<8;++h)
    for (int m=32;m;m>>=1){ pm[h] += __shfl_xor(pm[h],m); pd[h] += __shfl_xor(pd[h],m); }
  __shared__ float r2[4][16];
  int wv = tid>>6;
  if ((tid&63)==0) {
#pragma unroll
    for (int h=0;h<8;++h){ r2[wv][h]=pm[h]; r2[wv][8+h]=pd[h]; }
  }
  __syncthreads();
  if (tid < 16) {
    float s = r2[0][tid]+r2[1][tid]+r2[2][tid]+r2[3][tid];
    if (tid<8) mg[(b*8+tid)*64 + ch] = sigm(s);
    else d1m[(b*8+(tid-8))*64 + ch] = 1.f - sigm(s);
  }
}

// ---------------- generic bf16 GEMM: C = A(MxK) @ Bt(NxK)^T ----------------
// 512 threads, 8 waves (2M x 4N), wave tile 64x32, double-buffered LDS (64KB),
// issue-early staging: STAGE(next) -> ds_read+MFMA(cur) -> vmcnt(0)+barrier.
// kvT != nullptr (kv GEMM only): keys half (col<1024) additionally stored as
// per-chunk transposed tiles kT[chunk][d:128][r:64] (XOR-swizzled).

__global__ __launch_bounds__(512, 4) void gemm_bt(
    const u16* __restrict__ A, const u16* __restrict__ Bt,
    void* __restrict__ C, int M, int N, int K, int out_f32,
    u16* __restrict__ kvT)
{
  __shared__ __align__(16) u16 As[2][128*64];
  __shared__ __align__(16) u16 Bs[2][128*64];
  int tid = threadIdx.x;
  int w = tid>>6, lane = tid&63;
  int wr = w>>2, wc = w&3;
  int l15 = lane&15, l4 = lane>>4;
  int rl = lane>>3;
  int cg = (lane&7) ^ rl;
  int nwg = gridDim.x*gridDim.y;
  int wg  = blockIdx.y*gridDim.x + blockIdx.x;
  int cpx = nwg >> 3;
  int swz = (wg & 7)*cpx + (wg >> 3);
  int bx = swz % gridDim.x, by = swz / gridDim.x;
  int brow = by*128, bcol = bx*128;
  f32x4 acc[4][2] = {};

  auto STAGE = [&](int buf, int kt) {
#pragma unroll
    for (int i=0;i<2;++i) {
      int row = w*16 + i*8;
      gl16(&A [(size_t)(brow+row+rl)*K + kt + cg*8], &As[buf][row*64]);
      gl16(&Bt[(size_t)(bcol+row+rl)*K + kt + cg*8], &Bs[buf][row*64]);
    }
  };

  int nk = K >> 6;
  STAGE(0, 0);
  asm volatile("s_waitcnt vmcnt(0)");
  __syncthreads();
  for (int t=0; t<nk; ++t) {
    int cur = t & 1;
    if (t+1 < nk) STAGE(cur^1, (t+1)*64);
#pragma unroll
    for (int ks=0; ks<2; ++ks) {
      short8 af[4], bf[2];
#pragma unroll
      for (int m=0;m<4;++m) {
        int row = wr*64 + m*16 + l15;
        int g = ks*4 + l4;
        af[m] = *(const short8*)&As[cur][row*64 + ((g ^ (row&7))<<3)];
      }
#pragma unroll
      for (int n=0;n<2;++n) {
        int row = wc*32 + n*16 + l15;
        int g = ks*4 + l4;
        bf[n] = *(const short8*)&Bs[cur][row*64 + ((g ^ (row&7))<<3)];
      }
#pragma unroll
      for (int m=0;m<4;++m)
#pragma unroll
        for (int n=0;n<2;++n)
          acc[m][n] = __builtin_amdgcn_mfma_f32_16x16x32_bf16(af[m], bf[n], acc[m][n], 0,0,0);
    }
    asm volatile("s_waitcnt vmcnt(0)");
    __syncthreads();
  }
#pragma unroll
  for (int m=0;m<4;++m) {
#pragma unroll
    for (int n=0;n<2;++n) {
      int col = bcol + wc*32 + n*16 + l15;
#pragma unroll
      for (int j=0;j<4;++j) {
        int row = brow + wr*64 + m*16 + l4*4 + j;
        if (out_f32) ((float*)C)[(size_t)row*N + col] = acc[m][n][j];
        else ((u16*)C)[(size_t)row*N + col] = f2b(acc[m][n][j]);
      }
    }
  }
  if (kvT) {
#pragma unroll
    for (int m=0;m<4;++m) {
#pragma unroll
      for (int n=0;n<2;++n) {
        int col = bcol + wc*32 + n*16 + l15;
        if (col < 1024) {
          int row0 = brow + wr*64 + m*16 + l4*4;
          int d = col & 127;
          int chunk = ((row0>>12)*8 + (col>>7))*64 + ((row0&4095)>>6);
          int rr = row0 & 63;
          u32x2 p; p[0] = pk2(acc[m][n][0], acc[m][n][1]);
                   p[1] = pk2(acc[m][n][2], acc[m][n][3]);
          *(u32x2*)&kvT[(size_t)chunk*8192 + taddr(d, rr)] = p;
        }
      }
    }
  }
}

// ---------------- mlp_fwd ----------------

__global__ __launch_bounds__(512) void mlp_fwd(
    const u16* __restrict__ kvout, const float* __restrict__ lr,
    const u16* __restrict__ w0Ts, const u16* __restrict__ w1Ts,
    const u16* __restrict__ w1bs,
    u16* __restrict__ aTg, u16* __restrict__ dpTg, u16* __restrict__ dxTg)
{
  __shared__ __align__(16) u16 W0L[16384];
  __shared__ __align__(16) u16 W1L[16384];
  __shared__ __align__(16) u16 WBL[16384];
  __shared__ __align__(16) u16 abuf[16384];
  int tid = threadIdx.x;
  int w = tid>>6, lane = tid&63;
  int l15 = lane&15, l4 = lane>>4;
#pragma unroll
  for (int it=0; it<4; ++it) {
    int wb = it*512 + w*64;
    gl16((const short8*)w0Ts + wb + lane, (short8*)W0L + wb);
    gl16((const short8*)w1Ts + wb + lane, (short8*)W1L + wb);
    gl16((const short8*)w1bs + wb + lane, (short8*)WBL + wb);
  }
  __syncthreads();
  u16* ab = abuf + w*2048;
  int r0 = l4*4;
  int q = w&3, half = w>>2;
  int rb = q*16;
#pragma unroll
  for (int it2=0; it2<2; ++it2) {
    int cidx = blockIdx.x*4 + it2*2 + half;
    int bh = cidx>>6, ch = cidx&63;
    int b = bh>>3, hh = bh&7;
    size_t t0 = (size_t)(b*4096 + ch*64 + rb);
    size_t tout = (size_t)cidx*8192;
    f32x4 lrv = *(const f32x4*)&lr[(size_t)bh*4096 + ch*64 + rb + r0];

    f32x4 x1[8] = {};
#pragma unroll
    for (int ks=0; ks<4; ++ks) {
      short8 af = *(const short8*)&kvout[(t0 + l15)*2048 + hh*128 + ks*32 + l4*8];
#pragma unroll
      for (int n=0;n<8;++n) {
        short8 bf = frag_row_lds128(W0L, n*16+l15, ks, l4);
        x1[n] = __builtin_amdgcn_mfma_f32_16x16x32_bf16(af, bf, x1[n], 0,0,0);
      }
    }
#pragma unroll
    for (int n=0;n<8;++n) {
      int c = n*16 + l15;
      float av[4];
#pragma unroll
      for (int j=0;j<4;++j){ float xv = x1[n][j]; av[j] = xv*sigm(xv); }
      ab[sidx(r0+0,c)] = f2b(av[0]);
      ab[sidx(r0+1,c)] = f2b(av[1]);
      ab[sidx(r0+2,c)] = f2b(av[2]);
      ab[sidx(r0+3,c)] = f2b(av[3]);
      u32x2 p; p[0] = pk2(av[0],av[1]); p[1] = pk2(av[2],av[3]);
      *(u32x2*)&aTg[tout + taddr(c, rb + r0)] = p;
    }
    f32x4 pr[8] = {};
#pragma unroll
    for (int ks=0; ks<4; ++ks) {
      short8 af = frag_row_lds128(ab, l15, ks, l4);
#pragma unroll
      for (int n=0;n<8;++n) {
        short8 bf = frag_row_lds128(W1L, n*16+l15, ks, l4);
        pr[n] = __builtin_amdgcn_mfma_f32_16x16x32_bf16(af, bf, pr[n], 0,0,0);
      }
    }
#pragma unroll
    for (int n=0;n<8;++n) {
      int c = n*16 + l15;
      float dv[4];
#pragma unroll
      for (int j=0;j<4;++j) {
        float vv = b2f(kvout[(t0+r0+j)*2048 + 1024 + hh*128 + c]);
        dv[j] = 0.015625f * lrv[j] * (pr[n][j] - vv);
      }
      ab[sidx(r0+0,c)] = f2b(dv[0]);
      ab[sidx(r0+1,c)] = f2b(dv[1]);
      ab[sidx(r0+2,c)] = f2b(dv[2]);
      ab[sidx(r0+3,c)] = f2b(dv[3]);
      u32x2 p; p[0] = pk2(dv[0],dv[1]); p[1] = pk2(dv[2],dv[3]);
      *(u32x2*)&dpTg[tout + taddr(c, rb + r0)] = p;
    }
    f32x4 da[8] = {};
#pragma unroll
    for (int ks=0; ks<4; ++ks) {
      short8 af = frag_row_lds128(ab, l15, ks, l4);
#pragma unroll
      for (int n=0;n<8;++n) {
        short8 bf = frag_row_lds128(WBL, n*16+l15, ks, l4);
        da[n] = __builtin_amdgcn_mfma_f32_16x16x32_bf16(af, bf, da[n], 0,0,0);
      }
    }
#pragma unroll
    for (int n=0;n<8;++n) {
      int c = n*16 + l15;
      float d[4];
#pragma unroll
      for (int j=0;j<4;++j) {
        float xv = x1[n][j];
        float sg = sigm(xv);
        d[j] = da[n][j]*(sg*(1.f + xv*(1.f - sg)));
      }
      u32x2 p; p[0] = pk2(d[0],d[1]); p[1] = pk2(d[2],d[3]);
      *(u32x2*)&dxTg[tout + taddr(c, rb + r0)] = p;
    }
  }
}

// ---------------- grad_op ----------------

__global__ __launch_bounds__(256) void grad_op(
    const u16* __restrict__ dpT, const u16* __restrict__ aT,
    const u16* __restrict__ dxT, const u16* __restrict__ kT,
    u16* __restrict__ S)
{
  __shared__ __align__(16) u16 lds[16384];
  int bid = blockIdx.x;
  int op = bid >> 10;
  int sub = bid & 1023, bh = sub>>6, ch = sub&63;
  size_t tin = (size_t)sub*8192;
  const u16* Ain = op ? (dxT + tin) : (dpT + tin);
  const u16* Bin = op ? (kT  + tin) : (aT  + tin);
  int tid = threadIdx.x;
  int w = tid>>6, lane = tid&63;
  int l15 = lane&15, l4 = lane>>4;

#pragma unroll
  for (int it=0; it<4; ++it) {
    int wb = it*256 + w*64;
    gl16((const short8*)Ain + wb + lane, (short8*)lds + wb);
    gl16((const short8*)Bin + wb + lane, (short8*)(lds+8192) + wb);
  }
  __syncthreads();

  f32x4 g[2][8] = {};
#pragma unroll
  for (int ks=0; ks<2; ++ks) {
    short8 af[2];
#pragma unroll
    for (int mi=0; mi<2; ++mi)
      af[mi] = frag_tile(lds, w*32 + mi*16 + l15, ks, l4);
#pragma unroll
    for (int n=0;n<8;++n) {
      short8 bf = frag_tile(lds+8192, n*16 + l15, ks, l4);
#pragma unroll
      for (int mi=0;mi<2;++mi)
        g[mi][n] = __builtin_amdgcn_mfma_f32_16x16x32_bf16(af[mi], bf, g[mi][n], 0,0,0);
    }
  }
  __syncthreads();

#pragma unroll
  for (int mi=0;mi<2;++mi)
#pragma unroll
    for (int n=0;n<8;++n)
#pragma unroll
      for (int j=0;j<4;++j) {
        int m = w*32 + mi*16 + l4*4 + j, c = n*16 + l15;
        lds[sidx(m,c)] = f2b(-g[mi][n][j]);
      }
  __syncthreads();

  u16* Sout = S + ((size_t)((op ? bh : 16+bh))*64 + ch)*16384;
#pragma unroll
  for (int it=0; it<8; ++it)
    ((short8*)Sout)[it*256+tid] = ((const short8*)lds)[it*256+tid];
}

// ---- scan: double linear recurrence, 2 elements/thread (u32 packed) ----

__global__ __launch_bounds__(256) void scan_kernel(
    u16* __restrict__ S, const float* __restrict__ mg, const float* __restrict__ d1m,
    const u16* __restrict__ w0Ts, const u16* __restrict__ w1Ts)
{
  int bidx = blockIdx.x;              // mbh*32 + eblk
  int eblk = bidx & 31;
  int mbh = bidx >> 5;
  int bh = mbh & 15;
  int e = (eblk*256 + threadIdx.x)*2;
  uint32_t* base = (uint32_t*)(S + (size_t)mbh*64*16384 + e);
  const u16* wsrc = (mbh < 16) ? w0Ts : w1Ts;
  uint32_t wp = *(const uint32_t*)&wsrc[e];
  float wv0 = b2f((u16)(wp & 0xffffu)), wv1 = b2f((u16)(wp >> 16));
  const float* g1 = mg + bh*64;
  const float* g2 = d1m + bh*64;
  float mom0=0.f, upd0=0.f, mom1=0.f, upd1=0.f;
  for (int c2=0; c2<64; ++c2) {
    uint32_t s2 = base[(size_t)c2*8192];
    float s0 = b2f((u16)(s2 & 0xffffu)), s1 = b2f((u16)(s2 >> 16));
    float gg1 = g1[c2], gg2 = g2[c2];
    mom0 = gg1*mom0 + s0; upd0 = gg2*upd0 + mom0;
    mom1 = gg1*mom1 + s1; upd1 = gg2*upd1 + mom1;
    base[(size_t)c2*8192] = pk2(wv0 + upd0, wv1 + upd1);
  }
}

// ---------------- retrieval (ch==0 blocks also zero the pad rows) ----------------

__global__ __launch_bounds__(256) void retrieve_kernel(
    const u16* __restrict__ qn, const u16* __restrict__ W,
    const float* __restrict__ gamma, const float* __restrict__ gate,
    u16* __restrict__ vals)
{
  __shared__ __align__(16) u16 W0s[16384];
  __shared__ __align__(16) u16 W1s[16384];
  __shared__ __align__(16) u16 QA[8192];
  int bid = blockIdx.x;
  int bh = bid>>6, ch = bid&63;
  int b = bh>>3, h = bh&7;
  int tid = threadIdx.x;
  int w = tid>>6, lane = tid&63;
  int l15 = lane&15, l4 = lane>>4;
  const u16* W0g = W + ((size_t)bh*64 + ch)*16384;
  const u16* W1g = W + ((size_t)(16+bh)*64 + ch)*16384;
#pragma unroll
  for (int it=0; it<8; ++it) {
    int wb = it*256 + w*64;
    gl16((const short8*)W0g + wb + lane, (short8*)W0s + wb);
    gl16((const short8*)W1g + wb + lane, (short8*)W1s + wb);
  }
  if (ch == 0) {
    for (int r = w; r < 63; r += 4)
      *(uint32_t*)&vals[((size_t)(b*4096 + r))*1024 + h*128 + lane*2] = 0;
  }
  u16* qa = QA + w*2048;
#pragma unroll
  for (int it=0; it<4; ++it) {
    int task = it*64 + lane;
    int rloc = task>>4, g = task&15;
    int posn = ch*64 + w*16 + rloc + 63;
    short8 v;
    if (posn < 4096) v = *(const short8*)&qn[((size_t)(b*4096+posn))*1024 + h*128 + g*8];
    else {
#pragma unroll
      for (int i=0;i<8;++i) v[i]=0;
    }
    *(short8*)&qa[rloc*128 + ((g ^ (rloc&7))<<3)] = v;
  }
  __syncthreads();
  f32x4 xx[8] = {};
#pragma unroll
  for (int ks=0; ks<4; ++ks) {
    short8 af = frag_row_lds128(qa, l15, ks, l4);
#pragma unroll
    for (int n=0;n<8;++n) {
      short8 bf = frag_row_lds128(W0s, n*16+l15, ks, l4);
      xx[n] = __builtin_amdgcn_mfma_f32_16x16x32_bf16(af, bf, xx[n], 0,0,0);
    }
  }
  int r0 = l4*4;
#pragma unroll
  for (int n=0;n<8;++n) {
    int c = n*16 + l15;
#pragma unroll
    for (int j=0;j<4;++j) {
      float xv = xx[n][j];
      qa[sidx(r0+j,c)] = f2b(xv * sigm(xv));
    }
  }
  f32x4 vv[8] = {};
#pragma unroll
  for (int ks=0; ks<4; ++ks) {
    short8 af = frag_row_lds128(qa, l15, ks, l4);
#pragma unroll
    for (int n=0;n<8;++n) {
      short8 bf = frag_row_lds128(W1s, n*16+l15, ks, l4);
      vv[n] = __builtin_amdgcn_mfma_f32_16x16x32_bf16(af, bf, vv[n], 0,0,0);
    }
  }
#pragma unroll
  for (int j=0;j<4;++j) {
    float ssq = 0.f;
#pragma unroll
    for (int n=0;n<8;++n) ssq += vv[n][j]*vv[n][j];
    ssq += __shfl_xor(ssq,1); ssq += __shfl_xor(ssq,2);
    ssq += __shfl_xor(ssq,4); ssq += __shfl_xor(ssq,8);
    float rms = rsqrtf(ssq*(1.f/128.f) + 1e-6f);
    int posn = ch*64 + w*16 + r0 + j + 63;
    if (posn < 4096) {
      float gt = gate[(size_t)bh*4096 + posn];
      size_t orow = ((size_t)(b*4096+posn))*1024 + h*128;
#pragma unroll
      for (int n=0;n<8;++n) {
        int c = n*16 + l15;
        vals[orow + c] = f2b(vv[n][j]*rms*(1.f + gamma[h*128+c])*gt);
      }
    }
  }
}

extern "C" void kernel_launch(void* const* d_in, const int* in_sizes, int n_in,
                              void* d_out, int out_size, void* d_ws, size_t ws_size,
                              hipStream_t stream) {
  const float* seq    = (const float*)d_in[0];
  const float* gstore = (const float*)d_in[1];
  const float* gret   = (const float*)d_in[2];
  const float* wkv    = (const float*)d_in[3];
  const float* wq     = (const float*)d_in[4];
  const float* wstep  = (const float*)d_in[5];
  const float* wmom   = (const float*)d_in[6];
  const float* wdec   = (const float*)d_in[7];
  const float* wgatew = (const float*)d_in[8];
  const float* wcomb  = (const float*)d_in[9];
  const float* gamma  = (const float*)d_in[10];
  const float* w0f    = (const float*)d_in[11];
  const float* w1f    = (const float*)d_in[12];
  float* out = (float*)d_out;
  (void)in_sizes; (void)n_in; (void)out_size; (void)ws_size;

  char* p = (char*)d_ws;
  size_t off = 0;
  auto alloc = [&](size_t bytes) -> void* {
    void* r = p + off; off += (bytes + 255) & ~(size_t)255; return r;
  };
  u16* wkvT   = (u16*)alloc((size_t)2048*1024*2);
  u16* wqT    = (u16*)alloc((size_t)1024*1024*2);
  u16* wcombT = (u16*)alloc((size_t)1024*1024*2);
  u16* w0Ts   = (u16*)alloc(16384*2);
  u16* w1Ts   = (u16*)alloc(16384*2);
  u16* w1bs   = (u16*)alloc(16384*2);
  u16* Bt16   = (u16*)alloc(16384*2);
  u16* ss     = (u16*)alloc((size_t)NTOK*1024*2);
  u16* sr     = (u16*)alloc((size_t)NTOK*1024*2);
  u16* kvout  = (u16*)alloc((size_t)NTOK*2048*2);
  u16* qn     = (u16*)alloc((size_t)NTOK*1024*2);
  u16* vals   = (u16*)alloc((size_t)NTOK*1024*2);
  float* lr   = (float*)alloc((size_t)16*4096*4);
  float* gate = (float*)alloc((size_t)16*4096*4);
  float* mg   = (float*)alloc(1024*4);
  float* d1m  = (float*)alloc(1024*4);
  u16* S      = (u16*)alloc((size_t)32*64*16384*2);
  u16* kTg    = (u16*)alloc((size_t)1024*8192*2);
  u16* aTg    = (u16*)alloc((size_t)1024*8192*2);
  u16* dpTg   = (u16*)alloc((size_t)1024*8192*2);
  u16* dxTg   = (u16*)alloc((size_t)1024*8192*2);

  prep_all<<<dim3(1152),dim3(256),0,stream>>>(wkv, wq, wcomb, w0f, w1f, wstep, wgatew,
                                              wkvT, wqT, wcombT, w0Ts, w1Ts, w1bs, Bt16);
  norms_only<<<dim3(2048),dim3(256),0,stream>>>(seq, gstore, gret, ss, sr);
  proj_kernel<<<dim3(512),dim3(64),0,stream>>>(ss, sr, Bt16, lr, gate);
  chunkgates_kernel<<<dim3(128),dim3(256),0,stream>>>(ss, wmom, wdec, mg, d1m);
  gemm_bt<<<dim3(16,64),dim3(512),0,stream>>>(ss, wkvT, kvout, 8192, 2048, 1024, 0, kTg);
  gemm_bt<<<dim3(8,64),dim3(512),0,stream>>>(sr, wqT, qn, 8192, 1024, 1024, 0, nullptr);
  mlp_fwd<<<dim3(256),dim3(512),0,stream>>>(kvout, lr, w0Ts, w1Ts, w1bs, aTg, dpTg, dxTg);
  grad_op<<<dim3(2048),dim3(256),0,stream>>>(dpTg, aTg, dxTg, kTg, S);
  scan_kernel<<<dim3(1024),dim3(256),0,stream>>>(S, mg, d1m, w0Ts, w1Ts);
  retrieve_kernel<<<dim3(1024),dim3(256),0,stream>>>(qn, S, gamma, gate, vals);
  gemm_bt<<<dim3(8,64),dim3(512),0,stream>>>(vals, wcombT, out, 8192, 1024, 1024, 1, nullptr);
}

// Round 19
// 226.182 us; speedup vs baseline: 1.1408x; 1.0012x over previous
//
#include <hip/hip_runtime.h>
#include <stdint.h>

// NeuralMemory (Titans-style) for MI355X / gfx950.
//  prep_all (1 dispatch) -> norms_only + proj -> kv GEMM 256x256 (+kT epilogue)
//  / q GEMM 128x128 -> mlp_fwd (weights in LDS) -> grad_op -> scan -> retrieve
//  (ch==0 zeroes pad rows) -> combine GEMM 128x128.
//  gemm256 (kv only): 256x256 tile, 8 waves x (128x64), 2-buffer 128KB LDS,
//  1 blk/CU, issue-early global_load_lds; 4x MFMA-per-barrier vs 128x128.
//  gemm_bt (q/combine): r12/r18 measured-best 128x128 form.
//  [Failed: r11 3-buf; r13 counted-vmcnt; r14 fusion; r17 4-wave fat tile.]

#define SEQ 4096
#define NTOK 8192

typedef unsigned short u16;
typedef __attribute__((ext_vector_type(8))) short short8;
typedef __attribute__((ext_vector_type(4))) float f32x4;
typedef __attribute__((ext_vector_type(2))) unsigned int u32x2;

__device__ __forceinline__ u16 f2b(float f) {
  union { float f; uint32_t u; } c; c.f = f;
  uint32_t u = c.u;
  uint32_t r = (u + 0x7fffu + ((u >> 16) & 1u)) >> 16;
  return (u16)r;
}
__device__ __forceinline__ float b2f(u16 h) {
  union { uint32_t u; float f; } c; c.u = ((uint32_t)h) << 16;
  return c.f;
}
__device__ __forceinline__ float sigm(float x) { return 1.f / (1.f + __expf(-x)); }
__device__ __forceinline__ uint32_t pk2(float a, float b) {
  return (uint32_t)f2b(a) | ((uint32_t)f2b(b) << 16);
}
__device__ __forceinline__ void gl16(const void* g, void* l) {
  __builtin_amdgcn_global_load_lds(
      (const __attribute__((address_space(1))) unsigned int*)g,
      (__attribute__((address_space(3))) unsigned int*)l, 16, 0, 0);
}

__device__ __forceinline__ int sidx(int r, int c) {
  return r*128 + ((((c>>3) ^ (r&7))<<3) | (c&7));
}
__device__ __forceinline__ short8 frag_row_lds128(const u16* buf, int row, int ks, int l4) {
  int g = ks*4 + l4;
  return *(const short8*)&buf[row*128 + ((g ^ (row&7))<<3)];
}
__device__ __forceinline__ short8 frag_tile(const u16* t, int row, int ks, int l4) {
  return *(const short8*)&t[row*64 + (((ks*4 + l4) ^ (row&7))<<3)];
}
__device__ __forceinline__ int taddr(int c, int r0) {
  return c*64 + (r0 ^ ((c&7)<<3));
}

// ---------------- prep_all: all weight prep in one dispatch ----------------

__global__ __launch_bounds__(256) void prep_all(
    const float* __restrict__ wkv, const float* __restrict__ wq,
    const float* __restrict__ wcomb, const float* __restrict__ w0,
    const float* __restrict__ w1, const float* __restrict__ wstep,
    const float* __restrict__ wgatew,
    u16* __restrict__ wkvT, u16* __restrict__ wqT, u16* __restrict__ wcombT,
    u16* __restrict__ w0Ts, u16* __restrict__ w1Ts, u16* __restrict__ w1bs,
    u16* __restrict__ Bt16)
{
  __shared__ u16 tile[64*66];
  int bid = blockIdx.x;
  int tid = threadIdx.x;
  if (bid < 1024) {
    const float* src; u16* dst; int C; int bidx;
    if (bid < 512)      { src = wkv;   dst = wkvT;   C = 2048; bidx = bid; }
    else if (bid < 768) { src = wq;    dst = wqT;    C = 1024; bidx = bid - 512; }
    else                { src = wcomb; dst = wcombT; C = 1024; bidx = bid - 768; }
    const int R = 1024;
    int tiles_x = C >> 6;
    int tx = bidx % tiles_x, ty = bidx / tiles_x;
    int c0 = tx*64, r0 = ty*64;
#pragma unroll
    for (int it=0; it<16; ++it) {
      int idx = it*256 + tid;
      int rr = idx>>6, cc = idx&63;
      tile[cc*66 + rr] = f2b(src[(size_t)(r0+rr)*C + c0+cc]);
    }
    __syncthreads();
#pragma unroll
    for (int it=0; it<16; ++it) {
      int idx = it*256 + tid;
      int rr = idx>>6, cc = idx&63;
      dst[(size_t)(c0+rr)*R + r0+cc] = tile[rr*66 + cc];
    }
  } else if (bid < 1088) {
    int id = (bid-1024)*256 + tid;     // 0..16383
    int i = id>>7, j = id&127;
    float a = w0[id], b = w1[id];
    w0Ts[sidx(j,i)] = f2b(a);
    w1Ts[sidx(j,i)] = f2b(b);
    w1bs[sidx(i,j)] = f2b(b);
  } else {
    int id = (bid-1088)*256 + tid;     // 0..16383
    int n = id>>10, k = id&1023;
    float v = (n < 8) ? wstep[k*8 + n] : wgatew[k*8 + (n-8)];
    Bt16[id] = f2b(v);
  }
}

// ---------------- norms: streaming rmsnorm, one wave per token ----------------

__global__ __launch_bounds__(256) void norms_only(
    const float* __restrict__ seq, const float* __restrict__ gs,
    const float* __restrict__ gr, u16* __restrict__ ss, u16* __restrict__ sr)
{
  int w = threadIdx.x>>6, lane = threadIdx.x&63;
  int t = blockIdx.x*4 + w;
  const float* row = seq + (size_t)t*1024;
  f32x4 x[4];
  float ssq = 0.f;
#pragma unroll
  for (int j=0;j<4;++j) {
    x[j] = *(const f32x4*)&row[j*256 + lane*4];
    ssq += x[j][0]*x[j][0] + x[j][1]*x[j][1] + x[j][2]*x[j][2] + x[j][3]*x[j][3];
  }
  for (int m=32;m;m>>=1) ssq += __shfl_xor(ssq, m);
  float inv = rsqrtf(ssq*(1.f/1024.f) + 1e-6f);
#pragma unroll
  for (int j=0;j<4;++j) {
    int d = j*256 + lane*4;
    f32x4 g4 = *(const f32x4*)&gs[d];
    f32x4 r4 = *(const f32x4*)&gr[d];
    u32x2 ps, pr;
    ps[0] = pk2(x[j][0]*inv*g4[0], x[j][1]*inv*g4[1]);
    ps[1] = pk2(x[j][2]*inv*g4[2], x[j][3]*inv*g4[3]);
    pr[0] = pk2(x[j][0]*inv*r4[0], x[j][1]*inv*r4[1]);
    pr[1] = pk2(x[j][2]*inv*r4[2], x[j][3]*inv*r4[3]);
    *(u32x2*)&ss[(size_t)t*1024 + d] = ps;
    *(u32x2*)&sr[(size_t)t*1024 + d] = pr;
  }
}

// ---------------- proj: lr/gate via MFMA skinny GEMM ----------------

__global__ __launch_bounds__(64) void proj_kernel(
    const u16* __restrict__ ss, const u16* __restrict__ sr,
    const u16* __restrict__ Bt16, float* __restrict__ lr,
    float* __restrict__ gate)
{
  int lane = threadIdx.x;
  int l15 = lane&15, l4 = lane>>4;
  size_t t0 = (size_t)blockIdx.x*16;
  f32x4 acc1 = {}, acc2 = {};
#pragma unroll 8
  for (int ks=0; ks<32; ++ks) {
    int kof = ks*32 + l4*8;
    short8 bf = *(const short8*)&Bt16[l15*1024 + kof];
    short8 as = *(const short8*)&ss[(t0+l15)*1024 + kof];
    short8 ar = *(const short8*)&sr[(t0+l15)*1024 + kof];
    acc1 = __builtin_amdgcn_mfma_f32_16x16x32_bf16(as, bf, acc1, 0,0,0);
    acc2 = __builtin_amdgcn_mfma_f32_16x16x32_bf16(ar, bf, acc2, 0,0,0);
  }
  int col = l15;
#pragma unroll
  for (int j=0;j<4;++j) {
    int t = (int)t0 + l4*4 + j;
    int b = t>>12, pos = t&4095;
    if (col < 8) lr[((size_t)(b*8+col))*4096 + pos] = sigm(acc1[j])*0.01f;
    else gate[((size_t)(b*8+(col-8)))*4096 + pos] = sigm(acc2[j]);
  }
}

// ---------------- per-chunk gates from cmean (vectorized loads) ----------------

__global__ __launch_bounds__(256) void chunkgates_kernel(
    const u16* __restrict__ ss, const float* __restrict__ wmom,
    const float* __restrict__ wdec, float* __restrict__ mg,
    float* __restrict__ d1m)
{
  int bc = blockIdx.x; int b = bc>>6, ch = bc&63;
  size_t t0 = (size_t)(b*4096 + ch*64)*1024;
  int tid = threadIdx.x;
  int d0 = tid*4;
  float cm[4]; cm[0]=cm[1]=cm[2]=cm[3]=0.f;
  for (int tok=0; tok<64; ++tok) {
    u32x2 v2 = *(const u32x2*)&ss[t0 + (size_t)tok*1024 + d0];
    cm[0] += b2f((u16)(v2[0] & 0xffffu));
    cm[1] += b2f((u16)(v2[0] >> 16));
    cm[2] += b2f((u16)(v2[1] & 0xffffu));
    cm[3] += b2f((u16)(v2[1] >> 16));
  }
  float pm[8], pd[8];
#pragma unroll
  for (int h=0;h<8;++h){ pm[h]=0.f; pd[h]=0.f; }
#pragma unroll
  for (int i=0;i<4;++i) {
    float v = cm[i]*(1.f/64.f);
    int d = d0 + i;
#pragma unroll
    for (int h=0;h<8;++h){ pm[h]+=v*wmom[d*8+h]; pd[h]+=v*wdec[d*8+h]; }
  }
#pragma unroll
  for (int h=0;h<8;++h)
    for (int m=32;m;m>>=1){ pm[h] += __shfl_xor(pm[h],m); pd[h] += __shfl_xor(pd[h],m); }
  __shared__ float r2[4][16];
  int wv = tid>>6;
  if ((tid&63)==0) {
#pragma unroll
    for (int h=0;h<8;++h){ r2[wv][h]=pm[h]; r2[wv][8+h]=pd[h]; }
  }
  __syncthreads();
  if (tid < 16) {
    float s = r2[0][tid]+r2[1][tid]+r2[2][tid]+r2[3][tid];
    if (tid<8) mg[(b*8+tid)*64 + ch] = sigm(s);
    else d1m[(b*8+(tid-8))*64 + ch] = 1.f - sigm(s);
  }
}

// ---------------- gemm256: kv GEMM, 256x256 tile, bf16 out + kT epilogue ----------
// 512 threads, 8 waves (2M x 4N), wave tile 128x64 (acc 8x4), 2-buffer 128KB LDS,
// issue-early: STAGE(next) -> ds_read+64 MFMA/wave (cur) -> vmcnt(0)+barrier.
// Compute phase (~4x the 128^2 form) covers the staged loads' HBM latency.

__global__ __launch_bounds__(512) void gemm256(
    const u16* __restrict__ A, const u16* __restrict__ Bt,
    u16* __restrict__ C, int M, int N, int K,
    u16* __restrict__ kvT)
{
  __shared__ __align__(16) u16 As[2][256*64];
  __shared__ __align__(16) u16 Bs[2][256*64];
  int tid = threadIdx.x;
  int w = tid>>6, lane = tid&63;
  int wr = w>>2, wc = w&3;          // wave tile: rows wr*128.., cols wc*64..
  int l15 = lane&15, l4 = lane>>4;
  int rl = lane>>3;
  int cg = (lane&7) ^ rl;
  int nwg = gridDim.x*gridDim.y;
  int wg  = blockIdx.y*gridDim.x + blockIdx.x;
  int cpx = nwg >> 3;
  int swz = (wg & 7)*cpx + (wg >> 3);
  int bx = swz % gridDim.x, by = swz / gridDim.x;
  int brow = by*256, bcol = bx*256;
  f32x4 acc[8][4] = {};

  auto STAGE = [&](int buf, int kt) {
#pragma unroll
    for (int i=0;i<4;++i) {
      int row = i*64 + w*8;
      gl16(&A [(size_t)(brow+row+rl)*K + kt + cg*8], &As[buf][row*64]);
      gl16(&Bt[(size_t)(bcol+row+rl)*K + kt + cg*8], &Bs[buf][row*64]);
    }
  };

  int nk = K >> 6;
  STAGE(0, 0);
  asm volatile("s_waitcnt vmcnt(0)");
  __syncthreads();
  for (int t=0; t<nk; ++t) {
    int cur = t & 1;
    if (t+1 < nk) STAGE(cur^1, (t+1)*64);
#pragma unroll
    for (int ks=0; ks<2; ++ks) {
      short8 af[8], bf[4];
#pragma unroll
      for (int m=0;m<8;++m) {
        int row = wr*128 + m*16 + l15;
        int g = ks*4 + l4;
        af[m] = *(const short8*)&As[cur][row*64 + ((g ^ (row&7))<<3)];
      }
#pragma unroll
      for (int n=0;n<4;++n) {
        int row = wc*64 + n*16 + l15;
        int g = ks*4 + l4;
        bf[n] = *(const short8*)&Bs[cur][row*64 + ((g ^ (row&7))<<3)];
      }
#pragma unroll
      for (int m=0;m<8;++m)
#pragma unroll
        for (int n=0;n<4;++n)
          acc[m][n] = __builtin_amdgcn_mfma_f32_16x16x32_bf16(af[m], bf[n], acc[m][n], 0,0,0);
    }
    asm volatile("s_waitcnt vmcnt(0)");
    __syncthreads();
  }
#pragma unroll
  for (int m=0;m<8;++m) {
#pragma unroll
    for (int n=0;n<4;++n) {
      int col = bcol + wc*64 + n*16 + l15;
#pragma unroll
      for (int j=0;j<4;++j) {
        int row = brow + wr*128 + m*16 + l4*4 + j;
        C[(size_t)row*N + col] = f2b(acc[m][n][j]);
      }
    }
  }
#pragma unroll
  for (int m=0;m<8;++m) {
#pragma unroll
    for (int n=0;n<4;++n) {
      int col = bcol + wc*64 + n*16 + l15;
      if (col < 1024) {
        int row0 = brow + wr*128 + m*16 + l4*4;
        int d = col & 127;
        int chunk = ((row0>>12)*8 + (col>>7))*64 + ((row0&4095)>>6);
        int rr = row0 & 63;
        u32x2 p; p[0] = pk2(acc[m][n][0], acc[m][n][1]);
                 p[1] = pk2(acc[m][n][2], acc[m][n][3]);
        *(u32x2*)&kvT[(size_t)chunk*8192 + taddr(d, rr)] = p;
      }
    }
  }
}

// ---------------- gemm_bt: q/combine GEMM, 128x128 tile (r12 measured-best) ----

__global__ __launch_bounds__(512, 4) void gemm_bt(
    const u16* __restrict__ A, const u16* __restrict__ Bt,
    void* __restrict__ C, int M, int N, int K, int out_f32)
{
  __shared__ __align__(16) u16 As[2][128*64];
  __shared__ __align__(16) u16 Bs[2][128*64];
  int tid = threadIdx.x;
  int w = tid>>6, lane = tid&63;
  int wr = w>>2, wc = w&3;
  int l15 = lane&15, l4 = lane>>4;
  int rl = lane>>3;
  int cg = (lane&7) ^ rl;
  int nwg = gridDim.x*gridDim.y;
  int wg  = blockIdx.y*gridDim.x + blockIdx.x;
  int cpx = nwg >> 3;
  int swz = (wg & 7)*cpx + (wg >> 3);
  int bx = swz % gridDim.x, by = swz / gridDim.x;
  int brow = by*128, bcol = bx*128;
  f32x4 acc[4][2] = {};

  auto STAGE = [&](int buf, int kt) {
#pragma unroll
    for (int i=0;i<2;++i) {
      int row = w*16 + i*8;
      gl16(&A [(size_t)(brow+row+rl)*K + kt + cg*8], &As[buf][row*64]);
      gl16(&Bt[(size_t)(bcol+row+rl)*K + kt + cg*8], &Bs[buf][row*64]);
    }
  };

  int nk = K >> 6;
  STAGE(0, 0);
  asm volatile("s_waitcnt vmcnt(0)");
  __syncthreads();
  for (int t=0; t<nk; ++t) {
    int cur = t & 1;
    if (t+1 < nk) STAGE(cur^1, (t+1)*64);
#pragma unroll
    for (int ks=0; ks<2; ++ks) {
      short8 af[4], bf[2];
#pragma unroll
      for (int m=0;m<4;++m) {
        int row = wr*64 + m*16 + l15;
        int g = ks*4 + l4;
        af[m] = *(const short8*)&As[cur][row*64 + ((g ^ (row&7))<<3)];
      }
#pragma unroll
      for (int n=0;n<2;++n) {
        int row = wc*32 + n*16 + l15;
        int g = ks*4 + l4;
        bf[n] = *(const short8*)&Bs[cur][row*64 + ((g ^ (row&7))<<3)];
      }
#pragma unroll
      for (int m=0;m<4;++m)
#pragma unroll
        for (int n=0;n<2;++n)
          acc[m][n] = __builtin_amdgcn_mfma_f32_16x16x32_bf16(af[m], bf[n], acc[m][n], 0,0,0);
    }
    asm volatile("s_waitcnt vmcnt(0)");
    __syncthreads();
  }
#pragma unroll
  for (int m=0;m<4;++m) {
#pragma unroll
    for (int n=0;n<2;++n) {
      int col = bcol + wc*32 + n*16 + l15;
#pragma unroll
      for (int j=0;j<4;++j) {
        int row = brow + wr*64 + m*16 + l4*4 + j;
        if (out_f32) ((float*)C)[(size_t)row*N + col] = acc[m][n][j];
        else ((u16*)C)[(size_t)row*N + col] = f2b(acc[m][n][j]);
      }
    }
  }
}

// ---------------- mlp_fwd ----------------

__global__ __launch_bounds__(512) void mlp_fwd(
    const u16* __restrict__ kvout, const float* __restrict__ lr,
    const u16* __restrict__ w0Ts, const u16* __restrict__ w1Ts,
    const u16* __restrict__ w1bs,
    u16* __restrict__ aTg, u16* __restrict__ dpTg, u16* __restrict__ dxTg)
{
  __shared__ __align__(16) u16 W0L[16384];
  __shared__ __align__(16) u16 W1L[16384];
  __shared__ __align__(16) u16 WBL[16384];
  __shared__ __align__(16) u16 abuf[16384];
  int tid = threadIdx.x;
  int w = tid>>6, lane = tid&63;
  int l15 = lane&15, l4 = lane>>4;
#pragma unroll
  for (int it=0; it<4; ++it) {
    int wb = it*512 + w*64;
    gl16((const short8*)w0Ts + wb + lane, (short8*)W0L + wb);
    gl16((const short8*)w1Ts + wb + lane, (short8*)W1L + wb);
    gl16((const short8*)w1bs + wb + lane, (short8*)WBL + wb);
  }
  __syncthreads();
  u16* ab = abuf + w*2048;
  int r0 = l4*4;
  int q = w&3, half = w>>2;
  int rb = q*16;
#pragma unroll
  for (int it2=0; it2<2; ++it2) {
    int cidx = blockIdx.x*4 + it2*2 + half;
    int bh = cidx>>6, ch = cidx&63;
    int b = bh>>3, hh = bh&7;
    size_t t0 = (size_t)(b*4096 + ch*64 + rb);
    size_t tout = (size_t)cidx*8192;
    f32x4 lrv = *(const f32x4*)&lr[(size_t)bh*4096 + ch*64 + rb + r0];

    f32x4 x1[8] = {};
#pragma unroll
    for (int ks=0; ks<4; ++ks) {
      short8 af = *(const short8*)&kvout[(t0 + l15)*2048 + hh*128 + ks*32 + l4*8];
#pragma unroll
      for (int n=0;n<8;++n) {
        short8 bf = frag_row_lds128(W0L, n*16+l15, ks, l4);
        x1[n] = __builtin_amdgcn_mfma_f32_16x16x32_bf16(af, bf, x1[n], 0,0,0);
      }
    }
#pragma unroll
    for (int n=0;n<8;++n) {
      int c = n*16 + l15;
      float av[4];
#pragma unroll
      for (int j=0;j<4;++j){ float xv = x1[n][j]; av[j] = xv*sigm(xv); }
      ab[sidx(r0+0,c)] = f2b(av[0]);
      ab[sidx(r0+1,c)] = f2b(av[1]);
      ab[sidx(r0+2,c)] = f2b(av[2]);
      ab[sidx(r0+3,c)] = f2b(av[3]);
      u32x2 p; p[0] = pk2(av[0],av[1]); p[1] = pk2(av[2],av[3]);
      *(u32x2*)&aTg[tout + taddr(c, rb + r0)] = p;
    }
    f32x4 pr[8] = {};
#pragma unroll
    for (int ks=0; ks<4; ++ks) {
      short8 af = frag_row_lds128(ab, l15, ks, l4);
#pragma unroll
      for (int n=0;n<8;++n) {
        short8 bf = frag_row_lds128(W1L, n*16+l15, ks, l4);
        pr[n] = __builtin_amdgcn_mfma_f32_16x16x32_bf16(af, bf, pr[n], 0,0,0);
      }
    }
#pragma unroll
    for (int n=0;n<8;++n) {
      int c = n*16 + l15;
      float dv[4];
#pragma unroll
      for (int j=0;j<4;++j) {
        float vv = b2f(kvout[(t0+r0+j)*2048 + 1024 + hh*128 + c]);
        dv[j] = 0.015625f * lrv[j] * (pr[n][j] - vv);
      }
      ab[sidx(r0+0,c)] = f2b(dv[0]);
      ab[sidx(r0+1,c)] = f2b(dv[1]);
      ab[sidx(r0+2,c)] = f2b(dv[2]);
      ab[sidx(r0+3,c)] = f2b(dv[3]);
      u32x2 p; p[0] = pk2(dv[0],dv[1]); p[1] = pk2(dv[2],dv[3]);
      *(u32x2*)&dpTg[tout + taddr(c, rb + r0)] = p;
    }
    f32x4 da[8] = {};
#pragma unroll
    for (int ks=0; ks<4; ++ks) {
      short8 af = frag_row_lds128(ab, l15, ks, l4);
#pragma unroll
      for (int n=0;n<8;++n) {
        short8 bf = frag_row_lds128(WBL, n*16+l15, ks, l4);
        da[n] = __builtin_amdgcn_mfma_f32_16x16x32_bf16(af, bf, da[n], 0,0,0);
      }
    }
#pragma unroll
    for (int n=0;n<8;++n) {
      int c = n*16 + l15;
      float d[4];
#pragma unroll
      for (int j=0;j<4;++j) {
        float xv = x1[n][j];
        float sg = sigm(xv);
        d[j] = da[n][j]*(sg*(1.f + xv*(1.f - sg)));
      }
      u32x2 p; p[0] = pk2(d[0],d[1]); p[1] = pk2(d[2],d[3]);
      *(u32x2*)&dxTg[tout + taddr(c, rb + r0)] = p;
    }
  }
}

// ---------------- grad_op ----------------

__global__ __launch_bounds__(256) void grad_op(
    const u16* __restrict__ dpT, const u16* __restrict__ aT,
    const u16* __restrict__ dxT, const u16* __restrict__ kT,
    u16* __restrict__ S)
{
  __shared__ __align__(16) u16 lds[16384];
  int bid = blockIdx.x;
  int op = bid >> 10;
  int sub = bid & 1023, bh = sub>>6, ch = sub&63;
  size_t tin = (size_t)sub*8192;
  const u16* Ain = op ? (dxT + tin) : (dpT + tin);
  const u16* Bin = op ? (kT  + tin) : (aT  + tin);
  int tid = threadIdx.x;
  int w = tid>>6, lane = tid&63;
  int l15 = lane&15, l4 = lane>>4;

#pragma unroll
  for (int it=0; it<4; ++it) {
    int wb = it*256 + w*64;
    gl16((const short8*)Ain + wb + lane, (short8*)lds + wb);
    gl16((const short8*)Bin + wb + lane, (short8*)(lds+8192) + wb);
  }
  __syncthreads();

  f32x4 g[2][8] = {};
#pragma unroll
  for (int ks=0; ks<2; ++ks) {
    short8 af[2];
#pragma unroll
    for (int mi=0; mi<2; ++mi)
      af[mi] = frag_tile(lds, w*32 + mi*16 + l15, ks, l4);
#pragma unroll
    for (int n=0;n<8;++n) {
      short8 bf = frag_tile(lds+8192, n*16 + l15, ks, l4);
#pragma unroll
      for (int mi=0;mi<2;++mi)
        g[mi][n] = __builtin_amdgcn_mfma_f32_16x16x32_bf16(af[mi], bf, g[mi][n], 0,0,0);
    }
  }
  __syncthreads();

#pragma unroll
  for (int mi=0;mi<2;++mi)
#pragma unroll
    for (int n=0;n<8;++n)
#pragma unroll
      for (int j=0;j<4;++j) {
        int m = w*32 + mi*16 + l4*4 + j, c = n*16 + l15;
        lds[sidx(m,c)] = f2b(-g[mi][n][j]);
      }
  __syncthreads();

  u16* Sout = S + ((size_t)((op ? bh : 16+bh))*64 + ch)*16384;
#pragma unroll
  for (int it=0; it<8; ++it)
    ((short8*)Sout)[it*256+tid] = ((const short8*)lds)[it*256+tid];
}

// ---- scan: double linear recurrence, 2 elements/thread (u32 packed) ----

__global__ __launch_bounds__(256) void scan_kernel(
    u16* __restrict__ S, const float* __restrict__ mg, const float* __restrict__ d1m,
    const u16* __restrict__ w0Ts, const u16* __restrict__ w1Ts)
{
  int bidx = blockIdx.x;              // mbh*32 + eblk
  int eblk = bidx & 31;
  int mbh = bidx >> 5;
  int bh = mbh & 15;
  int e = (eblk*256 + threadIdx.x)*2;
  uint32_t* base = (uint32_t*)(S + (size_t)mbh*64*16384 + e);
  const u16* wsrc = (mbh < 16) ? w0Ts : w1Ts;
  uint32_t wp = *(const uint32_t*)&wsrc[e];
  float wv0 = b2f((u16)(wp & 0xffffu)), wv1 = b2f((u16)(wp >> 16));
  const float* g1 = mg + bh*64;
  const float* g2 = d1m + bh*64;
  float mom0=0.f, upd0=0.f, mom1=0.f, upd1=0.f;
  for (int c2=0; c2<64; ++c2) {
    uint32_t s2 = base[(size_t)c2*8192];
    float s0 = b2f((u16)(s2 & 0xffffu)), s1 = b2f((u16)(s2 >> 16));
    float gg1 = g1[c2], gg2 = g2[c2];
    mom0 = gg1*mom0 + s0; upd0 = gg2*upd0 + mom0;
    mom1 = gg1*mom1 + s1; upd1 = gg2*upd1 + mom1;
    base[(size_t)c2*8192] = pk2(wv0 + upd0, wv1 + upd1);
  }
}

// ---------------- retrieval (ch==0 blocks also zero the pad rows) ----------------

__global__ __launch_bounds__(256) void retrieve_kernel(
    const u16* __restrict__ qn, const u16* __restrict__ W,
    const float* __restrict__ gamma, const float* __restrict__ gate,
    u16* __restrict__ vals)
{
  __shared__ __align__(16) u16 W0s[16384];
  __shared__ __align__(16) u16 W1s[16384];
  __shared__ __align__(16) u16 QA[8192];
  int bid = blockIdx.x;
  int bh = bid>>6, ch = bid&63;
  int b = bh>>3, h = bh&7;
  int tid = threadIdx.x;
  int w = tid>>6, lane = tid&63;
  int l15 = lane&15, l4 = lane>>4;
  const u16* W0g = W + ((size_t)bh*64 + ch)*16384;
  const u16* W1g = W + ((size_t)(16+bh)*64 + ch)*16384;
#pragma unroll
  for (int it=0; it<8; ++it) {
    int wb = it*256 + w*64;
    gl16((const short8*)W0g + wb + lane, (short8*)W0s + wb);
    gl16((const short8*)W1g + wb + lane, (short8*)W1s + wb);
  }
  if (ch == 0) {
    for (int r = w; r < 63; r += 4)
      *(uint32_t*)&vals[((size_t)(b*4096 + r))*1024 + h*128 + lane*2] = 0;
  }
  u16* qa = QA + w*2048;
#pragma unroll
  for (int it=0; it<4; ++it) {
    int task = it*64 + lane;
    int rloc = task>>4, g = task&15;
    int posn = ch*64 + w*16 + rloc + 63;
    short8 v;
    if (posn < 4096) v = *(const short8*)&qn[((size_t)(b*4096+posn))*1024 + h*128 + g*8];
    else {
#pragma unroll
      for (int i=0;i<8;++i) v[i]=0;
    }
    *(short8*)&qa[rloc*128 + ((g ^ (rloc&7))<<3)] = v;
  }
  __syncthreads();
  f32x4 xx[8] = {};
#pragma unroll
  for (int ks=0; ks<4; ++ks) {
    short8 af = frag_row_lds128(qa, l15, ks, l4);
#pragma unroll
    for (int n=0;n<8;++n) {
      short8 bf = frag_row_lds128(W0s, n*16+l15, ks, l4);
      xx[n] = __builtin_amdgcn_mfma_f32_16x16x32_bf16(af, bf, xx[n], 0,0,0);
    }
  }
  int r0 = l4*4;
#pragma unroll
  for (int n=0;n<8;++n) {
    int c = n*16 + l15;
#pragma unroll
    for (int j=0;j<4;++j) {
      float xv = xx[n][j];
      qa[sidx(r0+j,c)] = f2b(xv * sigm(xv));
    }
  }
  f32x4 vv[8] = {};
#pragma unroll
  for (int ks=0; ks<4; ++ks) {
    short8 af = frag_row_lds128(qa, l15, ks, l4);
#pragma unroll
    for (int n=0;n<8;++n) {
      short8 bf = frag_row_lds128(W1s, n*16+l15, ks, l4);
      vv[n] = __builtin_amdgcn_mfma_f32_16x16x32_bf16(af, bf, vv[n], 0,0,0);
    }
  }
#pragma unroll
  for (int j=0;j<4;++j) {
    float ssq = 0.f;
#pragma unroll
    for (int n=0;n<8;++n) ssq += vv[n][j]*vv[n][j];
    ssq += __shfl_xor(ssq,1); ssq += __shfl_xor(ssq,2);
    ssq += __shfl_xor(ssq,4); ssq += __shfl_xor(ssq,8);
    float rms = rsqrtf(ssq*(1.f/128.f) + 1e-6f);
    int posn = ch*64 + w*16 + r0 + j + 63;
    if (posn < 4096) {
      float gt = gate[(size_t)bh*4096 + posn];
      size_t orow = ((size_t)(b*4096+posn))*1024 + h*128;
#pragma unroll
      for (int n=0;n<8;++n) {
        int c = n*16 + l15;
        vals[orow + c] = f2b(vv[n][j]*rms*(1.f + gamma[h*128+c])*gt);
      }
    }
  }
}

extern "C" void kernel_launch(void* const* d_in, const int* in_sizes, int n_in,
                              void* d_out, int out_size, void* d_ws, size_t ws_size,
                              hipStream_t stream) {
  const float* seq    = (const float*)d_in[0];
  const float* gstore = (const float*)d_in[1];
  const float* gret   = (const float*)d_in[2];
  const float* wkv    = (const float*)d_in[3];
  const float* wq     = (const float*)d_in[4];
  const float* wstep  = (const float*)d_in[5];
  const float* wmom   = (const float*)d_in[6];
  const float* wdec   = (const float*)d_in[7];
  const float* wgatew = (const float*)d_in[8];
  const float* wcomb  = (const float*)d_in[9];
  const float* gamma  = (const float*)d_in[10];
  const float* w0f    = (const float*)d_in[11];
  const float* w1f    = (const float*)d_in[12];
  float* out = (float*)d_out;
  (void)in_sizes; (void)n_in; (void)out_size; (void)ws_size;

  char* p = (char*)d_ws;
  size_t off = 0;
  auto alloc = [&](size_t bytes) -> void* {
    void* r = p + off; off += (bytes + 255) & ~(size_t)255; return r;
  };
  u16* wkvT   = (u16*)alloc((size_t)2048*1024*2);
  u16* wqT    = (u16*)alloc((size_t)1024*1024*2);
  u16* wcombT = (u16*)alloc((size_t)1024*1024*2);
  u16* w0Ts   = (u16*)alloc(16384*2);
  u16* w1Ts   = (u16*)alloc(16384*2);
  u16* w1bs   = (u16*)alloc(16384*2);
  u16* Bt16   = (u16*)alloc(16384*2);
  u16* ss     = (u16*)alloc((size_t)NTOK*1024*2);
  u16* sr     = (u16*)alloc((size_t)NTOK*1024*2);
  u16* kvout  = (u16*)alloc((size_t)NTOK*2048*2);
  u16* qn     = (u16*)alloc((size_t)NTOK*1024*2);
  u16* vals   = (u16*)alloc((size_t)NTOK*1024*2);
  float* lr   = (float*)alloc((size_t)16*4096*4);
  float* gate = (float*)alloc((size_t)16*4096*4);
  float* mg   = (float*)alloc(1024*4);
  float* d1m  = (float*)alloc(1024*4);
  u16* S      = (u16*)alloc((size_t)32*64*16384*2);
  u16* kTg    = (u16*)alloc((size_t)1024*8192*2);
  u16* aTg    = (u16*)alloc((size_t)1024*8192*2);
  u16* dpTg   = (u16*)alloc((size_t)1024*8192*2);
  u16* dxTg   = (u16*)alloc((size_t)1024*8192*2);

  prep_all<<<dim3(1152),dim3(256),0,stream>>>(wkv, wq, wcomb, w0f, w1f, wstep, wgatew,
                                              wkvT, wqT, wcombT, w0Ts, w1Ts, w1bs, Bt16);
  norms_only<<<dim3(2048),dim3(256),0,stream>>>(seq, gstore, gret, ss, sr);
  proj_kernel<<<dim3(512),dim3(64),0,stream>>>(ss, sr, Bt16, lr, gate);
  chunkgates_kernel<<<dim3(128),dim3(256),0,stream>>>(ss, wmom, wdec, mg, d1m);
  gemm256<<<dim3(8,32),dim3(512),0,stream>>>(ss, wkvT, kvout, 8192, 2048, 1024, kTg);
  gemm_bt<<<dim3(8,64),dim3(512),0,stream>>>(sr, wqT, qn, 8192, 1024, 1024, 0);
  mlp_fwd<<<dim3(256),dim3(512),0,stream>>>(kvout, lr, w0Ts, w1Ts, w1bs, aTg, dpTg, dxTg);
  grad_op<<<dim3(2048),dim3(256),0,stream>>>(dpTg, aTg, dxTg, kTg, S);
  scan_kernel<<<dim3(1024),dim3(256),0,stream>>>(S, mg, d1m, w0Ts, w1Ts);
  retrieve_kernel<<<dim3(1024),dim3(256),0,stream>>>(qn, S, gamma, gate, vals);
  gemm_bt<<<dim3(8,64),dim3(512),0,stream>>>(vals, wcombT, out, 8192, 1024, 1024, 1);
}

// Round 20
// 225.568 us; speedup vs baseline: 1.1439x; 1.0027x over previous
//
#include <hip/hip_runtime.h>
#include <stdint.h>

// NeuralMemory (Titans-style) for MI355X / gfx950.
//  prep_all (1 dispatch) -> norms_only + proj -> kv GEMM 256x256 (+kT epilogue)
//  / q GEMM 128x128 -> mlp_fwd (weights + V staged in LDS, 160KB) -> grad_op ->
//  scan -> retrieve (ch==0 zeroes pad rows) -> combine GEMM 128x128.
//  gemm256 (kv): 256x256, 8 waves x (128x64), 2-buffer 128KB, issue-early
//  global_load_lds (r19: neutral time vs 128^2 but FETCH halved -> keep).
//  [Failed: r11 3-buf; r13 counted-vmcnt; r14 fusion; r17 4-wave fat tile +
//   w1-from-global. GEMM 2-barrier family ceiling ~28% MfmaUtil, 6 variants.]

#define SEQ 4096
#define NTOK 8192

typedef unsigned short u16;
typedef __attribute__((ext_vector_type(8))) short short8;
typedef __attribute__((ext_vector_type(4))) float f32x4;
typedef __attribute__((ext_vector_type(2))) unsigned int u32x2;

__device__ __forceinline__ u16 f2b(float f) {
  union { float f; uint32_t u; } c; c.f = f;
  uint32_t u = c.u;
  uint32_t r = (u + 0x7fffu + ((u >> 16) & 1u)) >> 16;
  return (u16)r;
}
__device__ __forceinline__ float b2f(u16 h) {
  union { uint32_t u; float f; } c; c.u = ((uint32_t)h) << 16;
  return c.f;
}
__device__ __forceinline__ float sigm(float x) { return 1.f / (1.f + __expf(-x)); }
__device__ __forceinline__ uint32_t pk2(float a, float b) {
  return (uint32_t)f2b(a) | ((uint32_t)f2b(b) << 16);
}
__device__ __forceinline__ void gl16(const void* g, void* l) {
  __builtin_amdgcn_global_load_lds(
      (const __attribute__((address_space(1))) unsigned int*)g,
      (__attribute__((address_space(3))) unsigned int*)l, 16, 0, 0);
}

__device__ __forceinline__ int sidx(int r, int c) {
  return r*128 + ((((c>>3) ^ (r&7))<<3) | (c&7));
}
__device__ __forceinline__ short8 frag_row_lds128(const u16* buf, int row, int ks, int l4) {
  int g = ks*4 + l4;
  return *(const short8*)&buf[row*128 + ((g ^ (row&7))<<3)];
}
__device__ __forceinline__ short8 frag_tile(const u16* t, int row, int ks, int l4) {
  return *(const short8*)&t[row*64 + (((ks*4 + l4) ^ (row&7))<<3)];
}
__device__ __forceinline__ int taddr(int c, int r0) {
  return c*64 + (r0 ^ ((c&7)<<3));
}

// ---------------- prep_all: all weight prep in one dispatch ----------------

__global__ __launch_bounds__(256) void prep_all(
    const float* __restrict__ wkv, const float* __restrict__ wq,
    const float* __restrict__ wcomb, const float* __restrict__ w0,
    const float* __restrict__ w1, const float* __restrict__ wstep,
    const float* __restrict__ wgatew,
    u16* __restrict__ wkvT, u16* __restrict__ wqT, u16* __restrict__ wcombT,
    u16* __restrict__ w0Ts, u16* __restrict__ w1Ts, u16* __restrict__ w1bs,
    u16* __restrict__ Bt16)
{
  __shared__ u16 tile[64*66];
  int bid = blockIdx.x;
  int tid = threadIdx.x;
  if (bid < 1024) {
    const float* src; u16* dst; int C; int bidx;
    if (bid < 512)      { src = wkv;   dst = wkvT;   C = 2048; bidx = bid; }
    else if (bid < 768) { src = wq;    dst = wqT;    C = 1024; bidx = bid - 512; }
    else                { src = wcomb; dst = wcombT; C = 1024; bidx = bid - 768; }
    const int R = 1024;
    int tiles_x = C >> 6;
    int tx = bidx % tiles_x, ty = bidx / tiles_x;
    int c0 = tx*64, r0 = ty*64;
#pragma unroll
    for (int it=0; it<16; ++it) {
      int idx = it*256 + tid;
      int rr = idx>>6, cc = idx&63;
      tile[cc*66 + rr] = f2b(src[(size_t)(r0+rr)*C + c0+cc]);
    }
    __syncthreads();
#pragma unroll
    for (int it=0; it<16; ++it) {
      int idx = it*256 + tid;
      int rr = idx>>6, cc = idx&63;
      dst[(size_t)(c0+rr)*R + r0+cc] = tile[rr*66 + cc];
    }
  } else if (bid < 1088) {
    int id = (bid-1024)*256 + tid;     // 0..16383
    int i = id>>7, j = id&127;
    float a = w0[id], b = w1[id];
    w0Ts[sidx(j,i)] = f2b(a);
    w1Ts[sidx(j,i)] = f2b(b);
    w1bs[sidx(i,j)] = f2b(b);
  } else {
    int id = (bid-1088)*256 + tid;     // 0..16383
    int n = id>>10, k = id&1023;
    float v = (n < 8) ? wstep[k*8 + n] : wgatew[k*8 + (n-8)];
    Bt16[id] = f2b(v);
  }
}

// ---------------- norms: streaming rmsnorm, one wave per token ----------------

__global__ __launch_bounds__(256) void norms_only(
    const float* __restrict__ seq, const float* __restrict__ gs,
    const float* __restrict__ gr, u16* __restrict__ ss, u16* __restrict__ sr)
{
  int w = threadIdx.x>>6, lane = threadIdx.x&63;
  int t = blockIdx.x*4 + w;
  const float* row = seq + (size_t)t*1024;
  f32x4 x[4];
  float ssq = 0.f;
#pragma unroll
  for (int j=0;j<4;++j) {
    x[j] = *(const f32x4*)&row[j*256 + lane*4];
    ssq += x[j][0]*x[j][0] + x[j][1]*x[j][1] + x[j][2]*x[j][2] + x[j][3]*x[j][3];
  }
  for (int m=32;m;m>>=1) ssq += __shfl_xor(ssq, m);
  float inv = rsqrtf(ssq*(1.f/1024.f) + 1e-6f);
#pragma unroll
  for (int j=0;j<4;++j) {
    int d = j*256 + lane*4;
    f32x4 g4 = *(const f32x4*)&gs[d];
    f32x4 r4 = *(const f32x4*)&gr[d];
    u32x2 ps, pr;
    ps[0] = pk2(x[j][0]*inv*g4[0], x[j][1]*inv*g4[1]);
    ps[1] = pk2(x[j][2]*inv*g4[2], x[j][3]*inv*g4[3]);
    pr[0] = pk2(x[j][0]*inv*r4[0], x[j][1]*inv*r4[1]);
    pr[1] = pk2(x[j][2]*inv*r4[2], x[j][3]*inv*r4[3]);
    *(u32x2*)&ss[(size_t)t*1024 + d] = ps;
    *(u32x2*)&sr[(size_t)t*1024 + d] = pr;
  }
}

// ---------------- proj: lr/gate via MFMA skinny GEMM ----------------

__global__ __launch_bounds__(64) void proj_kernel(
    const u16* __restrict__ ss, const u16* __restrict__ sr,
    const u16* __restrict__ Bt16, float* __restrict__ lr,
    float* __restrict__ gate)
{
  int lane = threadIdx.x;
  int l15 = lane&15, l4 = lane>>4;
  size_t t0 = (size_t)blockIdx.x*16;
  f32x4 acc1 = {}, acc2 = {};
#pragma unroll 8
  for (int ks=0; ks<32; ++ks) {
    int kof = ks*32 + l4*8;
    short8 bf = *(const short8*)&Bt16[l15*1024 + kof];
    short8 as = *(const short8*)&ss[(t0+l15)*1024 + kof];
    short8 ar = *(const short8*)&sr[(t0+l15)*1024 + kof];
    acc1 = __builtin_amdgcn_mfma_f32_16x16x32_bf16(as, bf, acc1, 0,0,0);
    acc2 = __builtin_amdgcn_mfma_f32_16x16x32_bf16(ar, bf, acc2, 0,0,0);
  }
  int col = l15;
#pragma unroll
  for (int j=0;j<4;++j) {
    int t = (int)t0 + l4*4 + j;
    int b = t>>12, pos = t&4095;
    if (col < 8) lr[((size_t)(b*8+col))*4096 + pos] = sigm(acc1[j])*0.01f;
    else gate[((size_t)(b*8+(col-8)))*4096 + pos] = sigm(acc2[j]);
  }
}

// ---------------- per-chunk gates from cmean (vectorized loads) ----------------

__global__ __launch_bounds__(256) void chunkgates_kernel(
    const u16* __restrict__ ss, const float* __restrict__ wmom,
    const float* __restrict__ wdec, float* __restrict__ mg,
    float* __restrict__ d1m)
{
  int bc = blockIdx.x; int b = bc>>6, ch = bc&63;
  size_t t0 = (size_t)(b*4096 + ch*64)*1024;
  int tid = threadIdx.x;
  int d0 = tid*4;
  float cm[4]; cm[0]=cm[1]=cm[2]=cm[3]=0.f;
  for (int tok=0; tok<64; ++tok) {
    u32x2 v2 = *(const u32x2*)&ss[t0 + (size_t)tok*1024 + d0];
    cm[0] += b2f((u16)(v2[0] & 0xffffu));
    cm[1] += b2f((u16)(v2[0] >> 16));
    cm[2] += b2f((u16)(v2[1] & 0xffffu));
    cm[3] += b2f((u16)(v2[1] >> 16));
  }
  float pm[8], pd[8];
#pragma unroll
  for (int h=0;h<8;++h){ pm[h]=0.f; pd[h]=0.f; }
#pragma unroll
  for (int i=0;i<4;++i) {
    float v = cm[i]*(1.f/64.f);
    int d = d0 + i;
#pragma unroll
    for (int h=0;h<8;++h){ pm[h]+=v*wmom[d*8+h]; pd[h]+=v*wdec[d*8+h]; }
  }
#pragma unroll
  for (int h=0;h<8;++h)
    for (int m=32;m;m>>=1){ pm[h] += __shfl_xor(pm[h],m); pd[h] += __shfl_xor(pd[h],m); }
  __shared__ float r2[4][16];
  int wv = tid>>6;
  if ((tid&63)==0) {
#pragma unroll
    for (int h=0;h<8;++h){ r2[wv][h]=pm[h]; r2[wv][8+h]=pd[h]; }
  }
  __syncthreads();
  if (tid < 16) {
    float s = r2[0][tid]+r2[1][tid]+r2[2][tid]+r2[3][tid];
    if (tid<8) mg[(b*8+tid)*64 + ch] = sigm(s);
    else d1m[(b*8+(tid-8))*64 + ch] = 1.f - sigm(s);
  }
}

// ---------------- gemm256: kv GEMM, 256x256 tile, bf16 out + kT epilogue ----------

__global__ __launch_bounds__(512) void gemm256(
    const u16* __restrict__ A, const u16* __restrict__ Bt,
    u16* __restrict__ C, int M, int N, int K,
    u16* __restrict__ kvT)
{
  __shared__ __align__(16) u16 As[2][256*64];
  __shared__ __align__(16) u16 Bs[2][256*64];
  int tid = threadIdx.x;
  int w = tid>>6, lane = tid&63;
  int wr = w>>2, wc = w&3;
  int l15 = lane&15, l4 = lane>>4;
  int rl = lane>>3;
  int cg = (lane&7) ^ rl;
  int nwg = gridDim.x*gridDim.y;
  int wg  = blockIdx.y*gridDim.x + blockIdx.x;
  int cpx = nwg >> 3;
  int swz = (wg & 7)*cpx + (wg >> 3);
  int bx = swz % gridDim.x, by = swz / gridDim.x;
  int brow = by*256, bcol = bx*256;
  f32x4 acc[8][4] = {};

  auto STAGE = [&](int buf, int kt) {
#pragma unroll
    for (int i=0;i<4;++i) {
      int row = i*64 + w*8;
      gl16(&A [(size_t)(brow+row+rl)*K + kt + cg*8], &As[buf][row*64]);
      gl16(&Bt[(size_t)(bcol+row+rl)*K + kt + cg*8], &Bs[buf][row*64]);
    }
  };

  int nk = K >> 6;
  STAGE(0, 0);
  asm volatile("s_waitcnt vmcnt(0)");
  __syncthreads();
  for (int t=0; t<nk; ++t) {
    int cur = t & 1;
    if (t+1 < nk) STAGE(cur^1, (t+1)*64);
#pragma unroll
    for (int ks=0; ks<2; ++ks) {
      short8 af[8], bf[4];
#pragma unroll
      for (int m=0;m<8;++m) {
        int row = wr*128 + m*16 + l15;
        int g = ks*4 + l4;
        af[m] = *(const short8*)&As[cur][row*64 + ((g ^ (row&7))<<3)];
      }
#pragma unroll
      for (int n=0;n<4;++n) {
        int row = wc*64 + n*16 + l15;
        int g = ks*4 + l4;
        bf[n] = *(const short8*)&Bs[cur][row*64 + ((g ^ (row&7))<<3)];
      }
#pragma unroll
      for (int m=0;m<8;++m)
#pragma unroll
        for (int n=0;n<4;++n)
          acc[m][n] = __builtin_amdgcn_mfma_f32_16x16x32_bf16(af[m], bf[n], acc[m][n], 0,0,0);
    }
    asm volatile("s_waitcnt vmcnt(0)");
    __syncthreads();
  }
#pragma unroll
  for (int m=0;m<8;++m) {
#pragma unroll
    for (int n=0;n<4;++n) {
      int col = bcol + wc*64 + n*16 + l15;
#pragma unroll
      for (int j=0;j<4;++j) {
        int row = brow + wr*128 + m*16 + l4*4 + j;
        C[(size_t)row*N + col] = f2b(acc[m][n][j]);
      }
    }
  }
#pragma unroll
  for (int m=0;m<8;++m) {
#pragma unroll
    for (int n=0;n<4;++n) {
      int col = bcol + wc*64 + n*16 + l15;
      if (col < 1024) {
        int row0 = brow + wr*128 + m*16 + l4*4;
        int d = col & 127;
        int chunk = ((row0>>12)*8 + (col>>7))*64 + ((row0&4095)>>6);
        int rr = row0 & 63;
        u32x2 p; p[0] = pk2(acc[m][n][0], acc[m][n][1]);
                 p[1] = pk2(acc[m][n][2], acc[m][n][3]);
        *(u32x2*)&kvT[(size_t)chunk*8192 + taddr(d, rr)] = p;
      }
    }
  }
}

// ---------------- gemm_bt: q/combine GEMM, 128x128 tile (r12 measured-best) ----

__global__ __launch_bounds__(512, 4) void gemm_bt(
    const u16* __restrict__ A, const u16* __restrict__ Bt,
    void* __restrict__ C, int M, int N, int K, int out_f32)
{
  __shared__ __align__(16) u16 As[2][128*64];
  __shared__ __align__(16) u16 Bs[2][128*64];
  int tid = threadIdx.x;
  int w = tid>>6, lane = tid&63;
  int wr = w>>2, wc = w&3;
  int l15 = lane&15, l4 = lane>>4;
  int rl = lane>>3;
  int cg = (lane&7) ^ rl;
  int nwg = gridDim.x*gridDim.y;
  int wg  = blockIdx.y*gridDim.x + blockIdx.x;
  int cpx = nwg >> 3;
  int swz = (wg & 7)*cpx + (wg >> 3);
  int bx = swz % gridDim.x, by = swz / gridDim.x;
  int brow = by*128, bcol = bx*128;
  f32x4 acc[4][2] = {};

  auto STAGE = [&](int buf, int kt) {
#pragma unroll
    for (int i=0;i<2;++i) {
      int row = w*16 + i*8;
      gl16(&A [(size_t)(brow+row+rl)*K + kt + cg*8], &As[buf][row*64]);
      gl16(&Bt[(size_t)(bcol+row+rl)*K + kt + cg*8], &Bs[buf][row*64]);
    }
  };

  int nk = K >> 6;
  STAGE(0, 0);
  asm volatile("s_waitcnt vmcnt(0)");
  __syncthreads();
  for (int t=0; t<nk; ++t) {
    int cur = t & 1;
    if (t+1 < nk) STAGE(cur^1, (t+1)*64);
#pragma unroll
    for (int ks=0; ks<2; ++ks) {
      short8 af[4], bf[2];
#pragma unroll
      for (int m=0;m<4;++m) {
        int row = wr*64 + m*16 + l15;
        int g = ks*4 + l4;
        af[m] = *(const short8*)&As[cur][row*64 + ((g ^ (row&7))<<3)];
      }
#pragma unroll
      for (int n=0;n<2;++n) {
        int row = wc*32 + n*16 + l15;
        int g = ks*4 + l4;
        bf[n] = *(const short8*)&Bs[cur][row*64 + ((g ^ (row&7))<<3)];
      }
#pragma unroll
      for (int m=0;m<4;++m)
#pragma unroll
        for (int n=0;n<2;++n)
          acc[m][n] = __builtin_amdgcn_mfma_f32_16x16x32_bf16(af[m], bf[n], acc[m][n], 0,0,0);
    }
    asm volatile("s_waitcnt vmcnt(0)");
    __syncthreads();
  }
#pragma unroll
  for (int m=0;m<4;++m) {
#pragma unroll
    for (int n=0;n<2;++n) {
      int col = bcol + wc*32 + n*16 + l15;
#pragma unroll
      for (int j=0;j<4;++j) {
        int row = brow + wr*64 + m*16 + l4*4 + j;
        if (out_f32) ((float*)C)[(size_t)row*N + col] = acc[m][n][j];
        else ((u16*)C)[(size_t)row*N + col] = f2b(acc[m][n][j]);
      }
    }
  }
}

// ---------------- mlp_fwd: weights + V staged in LDS (160KB, 1 blk/CU) ----------

__global__ __launch_bounds__(512) void mlp_fwd(
    const u16* __restrict__ kvout, const float* __restrict__ lr,
    const u16* __restrict__ w0Ts, const u16* __restrict__ w1Ts,
    const u16* __restrict__ w1bs,
    u16* __restrict__ aTg, u16* __restrict__ dpTg, u16* __restrict__ dxTg)
{
  __shared__ __align__(16) u16 W0L[16384];
  __shared__ __align__(16) u16 W1L[16384];
  __shared__ __align__(16) u16 WBL[16384];
  __shared__ __align__(16) u16 abuf[16384];
  __shared__ __align__(16) u16 vbuf[16384];   // 8 waves x [16][128] V slices
  int tid = threadIdx.x;
  int w = tid>>6, lane = tid&63;
  int l15 = lane&15, l4 = lane>>4;
#pragma unroll
  for (int it=0; it<4; ++it) {
    int wb = it*512 + w*64;
    gl16((const short8*)w0Ts + wb + lane, (short8*)W0L + wb);
    gl16((const short8*)w1Ts + wb + lane, (short8*)W1L + wb);
    gl16((const short8*)w1bs + wb + lane, (short8*)WBL + wb);
  }
  __syncthreads();
  u16* ab = abuf + w*2048;
  u16* vb = vbuf + w*2048;
  int r0 = l4*4;
  int q = w&3, half = w>>2;
  int rb = q*16;
#pragma unroll
  for (int it2=0; it2<2; ++it2) {
    int cidx = blockIdx.x*4 + it2*2 + half;
    int bh = cidx>>6, ch = cidx&63;
    int b = bh>>3, hh = bh&7;
    size_t t0 = (size_t)(b*4096 + ch*64 + rb);
    size_t tout = (size_t)cidx*8192;
    f32x4 lrv = *(const f32x4*)&lr[(size_t)bh*4096 + ch*64 + rb + r0];

    // issue-early V staging: wave-private slice, lands under x1/pred compute
#pragma unroll
    for (int it=0; it<4; ++it)
      gl16(&kvout[(t0 + it*4 + (lane>>4))*2048 + 1024 + hh*128 + (lane&15)*8],
           vb + it*512);

    f32x4 x1[8] = {};
#pragma unroll
    for (int ks=0; ks<4; ++ks) {
      short8 af = *(const short8*)&kvout[(t0 + l15)*2048 + hh*128 + ks*32 + l4*8];
#pragma unroll
      for (int n=0;n<8;++n) {
        short8 bf = frag_row_lds128(W0L, n*16+l15, ks, l4);
        x1[n] = __builtin_amdgcn_mfma_f32_16x16x32_bf16(af, bf, x1[n], 0,0,0);
      }
    }
#pragma unroll
    for (int n=0;n<8;++n) {
      int c = n*16 + l15;
      float av[4];
#pragma unroll
      for (int j=0;j<4;++j){ float xv = x1[n][j]; av[j] = xv*sigm(xv); }
      ab[sidx(r0+0,c)] = f2b(av[0]);
      ab[sidx(r0+1,c)] = f2b(av[1]);
      ab[sidx(r0+2,c)] = f2b(av[2]);
      ab[sidx(r0+3,c)] = f2b(av[3]);
      u32x2 p; p[0] = pk2(av[0],av[1]); p[1] = pk2(av[2],av[3]);
      *(u32x2*)&aTg[tout + taddr(c, rb + r0)] = p;
    }
    f32x4 pr[8] = {};
#pragma unroll
    for (int ks=0; ks<4; ++ks) {
      short8 af = frag_row_lds128(ab, l15, ks, l4);
#pragma unroll
      for (int n=0;n<8;++n) {
        short8 bf = frag_row_lds128(W1L, n*16+l15, ks, l4);
        pr[n] = __builtin_amdgcn_mfma_f32_16x16x32_bf16(af, bf, pr[n], 0,0,0);
      }
    }
    // V staging complete (issued ~64 MFMAs ago)
    asm volatile("s_waitcnt vmcnt(0)");
#pragma unroll
    for (int n=0;n<8;++n) {
      int c = n*16 + l15;
      float dv[4];
#pragma unroll
      for (int j=0;j<4;++j)
        dv[j] = 0.015625f * lrv[j] * (pr[n][j] - b2f(vb[(r0+j)*128 + c]));
      ab[sidx(r0+0,c)] = f2b(dv[0]);
      ab[sidx(r0+1,c)] = f2b(dv[1]);
      ab[sidx(r0+2,c)] = f2b(dv[2]);
      ab[sidx(r0+3,c)] = f2b(dv[3]);
      u32x2 p; p[0] = pk2(dv[0],dv[1]); p[1] = pk2(dv[2],dv[3]);
      *(u32x2*)&dpTg[tout + taddr(c, rb + r0)] = p;
    }
    f32x4 da[8] = {};
#pragma unroll
    for (int ks=0; ks<4; ++ks) {
      short8 af = frag_row_lds128(ab, l15, ks, l4);
#pragma unroll
      for (int n=0;n<8;++n) {
        short8 bf = frag_row_lds128(WBL, n*16+l15, ks, l4);
        da[n] = __builtin_amdgcn_mfma_f32_16x16x32_bf16(af, bf, da[n], 0,0,0);
      }
    }
#pragma unroll
    for (int n=0;n<8;++n) {
      int c = n*16 + l15;
      float d[4];
#pragma unroll
      for (int j=0;j<4;++j) {
        float xv = x1[n][j];
        float sg = sigm(xv);
        d[j] = da[n][j]*(sg*(1.f + xv*(1.f - sg)));
      }
      u32x2 p; p[0] = pk2(d[0],d[1]); p[1] = pk2(d[2],d[3]);
      *(u32x2*)&dxTg[tout + taddr(c, rb + r0)] = p;
    }
  }
}

// ---------------- grad_op ----------------

__global__ __launch_bounds__(256) void grad_op(
    const u16* __restrict__ dpT, const u16* __restrict__ aT,
    const u16* __restrict__ dxT, const u16* __restrict__ kT,
    u16* __restrict__ S)
{
  __shared__ __align__(16) u16 lds[16384];
  int bid = blockIdx.x;
  int op = bid >> 10;
  int sub = bid & 1023, bh = sub>>6, ch = sub&63;
  size_t tin = (size_t)sub*8192;
  const u16* Ain = op ? (dxT + tin) : (dpT + tin);
  const u16* Bin = op ? (kT  + tin) : (aT  + tin);
  int tid = threadIdx.x;
  int w = tid>>6, lane = tid&63;
  int l15 = lane&15, l4 = lane>>4;

#pragma unroll
  for (int it=0; it<4; ++it) {
    int wb = it*256 + w*64;
    gl16((const short8*)Ain + wb + lane, (short8*)lds + wb);
    gl16((const short8*)Bin + wb + lane, (short8*)(lds+8192) + wb);
  }
  __syncthreads();

  f32x4 g[2][8] = {};
#pragma unroll
  for (int ks=0; ks<2; ++ks) {
    short8 af[2];
#pragma unroll
    for (int mi=0; mi<2; ++mi)
      af[mi] = frag_tile(lds, w*32 + mi*16 + l15, ks, l4);
#pragma unroll
    for (int n=0;n<8;++n) {
      short8 bf = frag_tile(lds+8192, n*16 + l15, ks, l4);
#pragma unroll
      for (int mi=0;mi<2;++mi)
        g[mi][n] = __builtin_amdgcn_mfma_f32_16x16x32_bf16(af[mi], bf, g[mi][n], 0,0,0);
    }
  }
  __syncthreads();

#pragma unroll
  for (int mi=0;mi<2;++mi)
#pragma unroll
    for (int n=0;n<8;++n)
#pragma unroll
      for (int j=0;j<4;++j) {
        int m = w*32 + mi*16 + l4*4 + j, c = n*16 + l15;
        lds[sidx(m,c)] = f2b(-g[mi][n][j]);
      }
  __syncthreads();

  u16* Sout = S + ((size_t)((op ? bh : 16+bh))*64 + ch)*16384;
#pragma unroll
  for (int it=0; it<8; ++it)
    ((short8*)Sout)[it*256+tid] = ((const short8*)lds)[it*256+tid];
}

// ---- scan: double linear recurrence, 2 elements/thread (u32 packed) ----

__global__ __launch_bounds__(256) void scan_kernel(
    u16* __restrict__ S, const float* __restrict__ mg, const float* __restrict__ d1m,
    const u16* __restrict__ w0Ts, const u16* __restrict__ w1Ts)
{
  int bidx = blockIdx.x;              // mbh*32 + eblk
  int eblk = bidx & 31;
  int mbh = bidx >> 5;
  int bh = mbh & 15;
  int e = (eblk*256 + threadIdx.x)*2;
  uint32_t* base = (uint32_t*)(S + (size_t)mbh*64*16384 + e);
  const u16* wsrc = (mbh < 16) ? w0Ts : w1Ts;
  uint32_t wp = *(const uint32_t*)&wsrc[e];
  float wv0 = b2f((u16)(wp & 0xffffu)), wv1 = b2f((u16)(wp >> 16));
  const float* g1 = mg + bh*64;
  const float* g2 = d1m + bh*64;
  float mom0=0.f, upd0=0.f, mom1=0.f, upd1=0.f;
  for (int c2=0; c2<64; ++c2) {
    uint32_t s2 = base[(size_t)c2*8192];
    float s0 = b2f((u16)(s2 & 0xffffu)), s1 = b2f((u16)(s2 >> 16));
    float gg1 = g1[c2], gg2 = g2[c2];
    mom0 = gg1*mom0 + s0; upd0 = gg2*upd0 + mom0;
    mom1 = gg1*mom1 + s1; upd1 = gg2*upd1 + mom1;
    base[(size_t)c2*8192] = pk2(wv0 + upd0, wv1 + upd1);
  }
}

// ---------------- retrieval (ch==0 blocks also zero the pad rows) ----------------

__global__ __launch_bounds__(256) void retrieve_kernel(
    const u16* __restrict__ qn, const u16* __restrict__ W,
    const float* __restrict__ gamma, const float* __restrict__ gate,
    u16* __restrict__ vals)
{
  __shared__ __align__(16) u16 W0s[16384];
  __shared__ __align__(16) u16 W1s[16384];
  __shared__ __align__(16) u16 QA[8192];
  int bid = blockIdx.x;
  int bh = bid>>6, ch = bid&63;
  int b = bh>>3, h = bh&7;
  int tid = threadIdx.x;
  int w = tid>>6, lane = tid&63;
  int l15 = lane&15, l4 = lane>>4;
  const u16* W0g = W + ((size_t)bh*64 + ch)*16384;
  const u16* W1g = W + ((size_t)(16+bh)*64 + ch)*16384;
#pragma unroll
  for (int it=0; it<8; ++it) {
    int wb = it*256 + w*64;
    gl16((const short8*)W0g + wb + lane, (short8*)W0s + wb);
    gl16((const short8*)W1g + wb + lane, (short8*)W1s + wb);
  }
  if (ch == 0) {
    for (int r = w; r < 63; r += 4)
      *(uint32_t*)&vals[((size_t)(b*4096 + r))*1024 + h*128 + lane*2] = 0;
  }
  u16* qa = QA + w*2048;
#pragma unroll
  for (int it=0; it<4; ++it) {
    int task = it*64 + lane;
    int rloc = task>>4, g = task&15;
    int posn = ch*64 + w*16 + rloc + 63;
    short8 v;
    if (posn < 4096) v = *(const short8*)&qn[((size_t)(b*4096+posn))*1024 + h*128 + g*8];
    else {
#pragma unroll
      for (int i=0;i<8;++i) v[i]=0;
    }
    *(short8*)&qa[rloc*128 + ((g ^ (rloc&7))<<3)] = v;
  }
  __syncthreads();
  f32x4 xx[8] = {};
#pragma unroll
  for (int ks=0; ks<4; ++ks) {
    short8 af = frag_row_lds128(qa, l15, ks, l4);
#pragma unroll
    for (int n=0;n<8;++n) {
      short8 bf = frag_row_lds128(W0s, n*16+l15, ks, l4);
      xx[n] = __builtin_amdgcn_mfma_f32_16x16x32_bf16(af, bf, xx[n], 0,0,0);
    }
  }
  int r0 = l4*4;
#pragma unroll
  for (int n=0;n<8;++n) {
    int c = n*16 + l15;
#pragma unroll
    for (int j=0;j<4;++j) {
      float xv = xx[n][j];
      qa[sidx(r0+j,c)] = f2b(xv * sigm(xv));
    }
  }
  f32x4 vv[8] = {};
#pragma unroll
  for (int ks=0; ks<4; ++ks) {
    short8 af = frag_row_lds128(qa, l15, ks, l4);
#pragma unroll
    for (int n=0;n<8;++n) {
      short8 bf = frag_row_lds128(W1s, n*16+l15, ks, l4);
      vv[n] = __builtin_amdgcn_mfma_f32_16x16x32_bf16(af, bf, vv[n], 0,0,0);
    }
  }
#pragma unroll
  for (int j=0;j<4;++j) {
    float ssq = 0.f;
#pragma unroll
    for (int n=0;n<8;++n) ssq += vv[n][j]*vv[n][j];
    ssq += __shfl_xor(ssq,1); ssq += __shfl_xor(ssq,2);
    ssq += __shfl_xor(ssq,4); ssq += __shfl_xor(ssq,8);
    float rms = rsqrtf(ssq*(1.f/128.f) + 1e-6f);
    int posn = ch*64 + w*16 + r0 + j + 63;
    if (posn < 4096) {
      float gt = gate[(size_t)bh*4096 + posn];
      size_t orow = ((size_t)(b*4096+posn))*1024 + h*128;
#pragma unroll
      for (int n=0;n<8;++n) {
        int c = n*16 + l15;
        vals[orow + c] = f2b(vv[n][j]*rms*(1.f + gamma[h*128+c])*gt);
      }
    }
  }
}

extern "C" void kernel_launch(void* const* d_in, const int* in_sizes, int n_in,
                              void* d_out, int out_size, void* d_ws, size_t ws_size,
                              hipStream_t stream) {
  const float* seq    = (const float*)d_in[0];
  const float* gstore = (const float*)d_in[1];
  const float* gret   = (const float*)d_in[2];
  const float* wkv    = (const float*)d_in[3];
  const float* wq     = (const float*)d_in[4];
  const float* wstep  = (const float*)d_in[5];
  const float* wmom   = (const float*)d_in[6];
  const float* wdec   = (const float*)d_in[7];
  const float* wgatew = (const float*)d_in[8];
  const float* wcomb  = (const float*)d_in[9];
  const float* gamma  = (const float*)d_in[10];
  const float* w0f    = (const float*)d_in[11];
  const float* w1f    = (const float*)d_in[12];
  float* out = (float*)d_out;
  (void)in_sizes; (void)n_in; (void)out_size; (void)ws_size;

  char* p = (char*)d_ws;
  size_t off = 0;
  auto alloc = [&](size_t bytes) -> void* {
    void* r = p + off; off += (bytes + 255) & ~(size_t)255; return r;
  };
  u16* wkvT   = (u16*)alloc((size_t)2048*1024*2);
  u16* wqT    = (u16*)alloc((size_t)1024*1024*2);
  u16* wcombT = (u16*)alloc((size_t)1024*1024*2);
  u16* w0Ts   = (u16*)alloc(16384*2);
  u16* w1Ts   = (u16*)alloc(16384*2);
  u16* w1bs   = (u16*)alloc(16384*2);
  u16* Bt16   = (u16*)alloc(16384*2);
  u16* ss     = (u16*)alloc((size_t)NTOK*1024*2);
  u16* sr     = (u16*)alloc((size_t)NTOK*1024*2);
  u16* kvout  = (u16*)alloc((size_t)NTOK*2048*2);
  u16* qn     = (u16*)alloc((size_t)NTOK*1024*2);
  u16* vals   = (u16*)alloc((size_t)NTOK*1024*2);
  float* lr   = (float*)alloc((size_t)16*4096*4);
  float* gate = (float*)alloc((size_t)16*4096*4);
  float* mg   = (float*)alloc(1024*4);
  float* d1m  = (float*)alloc(1024*4);
  u16* S      = (u16*)alloc((size_t)32*64*16384*2);
  u16* kTg    = (u16*)alloc((size_t)1024*8192*2);
  u16* aTg    = (u16*)alloc((size_t)1024*8192*2);
  u16* dpTg   = (u16*)alloc((size_t)1024*8192*2);
  u16* dxTg   = (u16*)alloc((size_t)1024*8192*2);

  prep_all<<<dim3(1152),dim3(256),0,stream>>>(wkv, wq, wcomb, w0f, w1f, wstep, wgatew,
                                              wkvT, wqT, wcombT, w0Ts, w1Ts, w1bs, Bt16);
  norms_only<<<dim3(2048),dim3(256),0,stream>>>(seq, gstore, gret, ss, sr);
  proj_kernel<<<dim3(512),dim3(64),0,stream>>>(ss, sr, Bt16, lr, gate);
  chunkgates_kernel<<<dim3(128),dim3(256),0,stream>>>(ss, wmom, wdec, mg, d1m);
  gemm256<<<dim3(8,32),dim3(512),0,stream>>>(ss, wkvT, kvout, 8192, 2048, 1024, kTg);
  gemm_bt<<<dim3(8,64),dim3(512),0,stream>>>(sr, wqT, qn, 8192, 1024, 1024, 0);
  mlp_fwd<<<dim3(256),dim3(512),0,stream>>>(kvout, lr, w0Ts, w1Ts, w1bs, aTg, dpTg, dxTg);
  grad_op<<<dim3(2048),dim3(256),0,stream>>>(dpTg, aTg, dxTg, kTg, S);
  scan_kernel<<<dim3(1024),dim3(256),0,stream>>>(S, mg, d1m, w0Ts, w1Ts);
  retrieve_kernel<<<dim3(1024),dim3(256),0,stream>>>(qn, S, gamma, gate, vals);
  gemm_bt<<<dim3(8,64),dim3(512),0,stream>>>(vals, wcombT, out, 8192, 1024, 1024, 1);
}